// Round 1
// baseline (2592.567 us; speedup 1.0000x reference)
//
#include <hip/hip_runtime.h>

// GCN 3-layer: x[N,512] -> GCNConv(512,64)+relu -> GCNConv(64,32)+relu ->
// GCNConv(32,16) -> Linear(16,7). Symmetric norm with self-loops.
// All fp32. Aggregation via f32 atomics (baseline; CSR candidate later).

static inline int ceil_div_i(long long a, long long b) { return (int)((a + b - 1) / b); }

// ---------------- degree / norm ----------------
__global__ __launch_bounds__(256) void count_dst_kernel(const int* __restrict__ dst, int E,
                                                        int* __restrict__ cnt) {
    int i = blockIdx.x * blockDim.x + threadIdx.x;
    if (i < E) atomicAdd(&cnt[dst[i]], 1);
}

__global__ __launch_bounds__(256) void dis_kernel(const int* __restrict__ cnt,
                                                  float* __restrict__ dis, int M) {
    int i = blockIdx.x * blockDim.x + threadIdx.x;
    if (i < M) dis[i] = rsqrtf((float)(cnt[i] + 1));  // +1: self-loop
}

// ---------------- GEMM1: [M,512] @ [512,64] -> [M,64] ----------------
// Tile: 64 rows x 64 cols, K-chunks of 32. 256 threads, 4x4 acc each.
__global__ __launch_bounds__(256) void gemm1_kernel(const float* __restrict__ x,
                                                    const float* __restrict__ W,
                                                    float* __restrict__ out, int M) {
    __shared__ float xs[64][36];  // pad 32->36 (keeps 16B align, breaks pow2 stride)
    __shared__ float ws[32][68];  // pad 64->68
    const int t = threadIdx.x;
    const int tx = t & 15;   // output group: cols tx*4..tx*4+3
    const int ty = t >> 4;   // node group:   rows ty*4..ty*4+3
    const int m0 = blockIdx.x * 64;

    float acc[4][4] = {};
    for (int k0 = 0; k0 < 512; k0 += 32) {
        // stage x tile: 64x32 floats = 512 float4, 2 per thread
        for (int i = t; i < 512; i += 256) {
            int r = i >> 3, c = (i & 7) * 4;
            int gm = m0 + r;
            float4 v = make_float4(0.f, 0.f, 0.f, 0.f);
            if (gm < M) v = *(const float4*)&x[(size_t)gm * 512 + k0 + c];
            xs[r][c] = v.x; xs[r][c + 1] = v.y; xs[r][c + 2] = v.z; xs[r][c + 3] = v.w;
        }
        // stage W tile: 32x64 floats = 512 float4
        for (int i = t; i < 512; i += 256) {
            int r = i >> 4, c = (i & 15) * 4;
            float4 v = *(const float4*)&W[(size_t)(k0 + r) * 64 + c];
            ws[r][c] = v.x; ws[r][c + 1] = v.y; ws[r][c + 2] = v.z; ws[r][c + 3] = v.w;
        }
        __syncthreads();
        #pragma unroll
        for (int kk = 0; kk < 32; ++kk) {
            float xv[4], wv[4];
            #pragma unroll
            for (int i = 0; i < 4; ++i) xv[i] = xs[ty * 4 + i][kk];
            #pragma unroll
            for (int j = 0; j < 4; ++j) wv[j] = ws[kk][tx * 4 + j];
            #pragma unroll
            for (int i = 0; i < 4; ++i)
                #pragma unroll
                for (int j = 0; j < 4; ++j) acc[i][j] += xv[i] * wv[j];
        }
        __syncthreads();
    }
    #pragma unroll
    for (int i = 0; i < 4; ++i) {
        int gm = m0 + ty * 4 + i;
        if (gm < M) {
            float4 v = make_float4(acc[i][0], acc[i][1], acc[i][2], acc[i][3]);
            *(float4*)&out[(size_t)gm * 64 + tx * 4] = v;
        }
    }
}

// ---------------- small GEMM: [M,K] @ [K,OUT] -> [M,OUT] ----------------
template <int K, int OUT, int NPB>
__global__ __launch_bounds__(256) void gemm_small_kernel(const float* __restrict__ h,
                                                         const float* __restrict__ W,
                                                         float* __restrict__ out, int M) {
    __shared__ float Ws[K * OUT];
    __shared__ float hs[NPB][K];
    const int t = threadIdx.x;
    for (int i = t; i < K * OUT; i += 256) Ws[i] = W[i];
    const int n0 = blockIdx.x * NPB;
    for (int i = t; i < NPB * K; i += 256) {
        int r = i / K, c = i % K;
        int gm = n0 + r;
        hs[r][c] = (gm < M) ? h[(size_t)gm * K + c] : 0.f;
    }
    __syncthreads();
    const int nl = t / OUT, o = t % OUT;
    float acc = 0.f;
    #pragma unroll
    for (int k = 0; k < K; ++k) acc += hs[nl][k] * Ws[k * OUT + o];
    int gm = n0 + nl;
    if (gm < M) out[(size_t)gm * OUT + o] = acc;
}

// ---------------- scatter: agg[dst] += norm * h[src], F floats/row ----------------
template <int F>
__global__ __launch_bounds__(256) void scatter_kernel(const int* __restrict__ src,
                                                      const int* __restrict__ dst,
                                                      const float* __restrict__ dis,
                                                      const float* __restrict__ h,
                                                      float* __restrict__ agg, int E) {
    constexpr int SH = (F == 64) ? 4 : (F == 32) ? 3 : 2;  // log2(F/4)
    int t = blockIdx.x * blockDim.x + threadIdx.x;
    int e = t >> SH;
    if (e >= E) return;
    int f = (t & ((1 << SH) - 1)) * 4;
    int s = src[e], d = dst[e];
    float nrm = dis[s] * dis[d];
    float4 v = *(const float4*)&h[(size_t)s * F + f];
    float* o = &agg[(size_t)d * F + f];
    atomicAdd(o + 0, v.x * nrm);
    atomicAdd(o + 1, v.y * nrm);
    atomicAdd(o + 2, v.z * nrm);
    atomicAdd(o + 3, v.w * nrm);
}

// ---------------- finalize: h = act(agg + dis^2 * h + b) ----------------
template <int F, bool RELU>
__global__ __launch_bounds__(256) void finalize_kernel(const float* __restrict__ agg,
                                                       float* __restrict__ h,
                                                       const float* __restrict__ dis,
                                                       const float* __restrict__ b, int M) {
    constexpr int SH = (F == 64) ? 4 : (F == 32) ? 3 : 2;
    int t = blockIdx.x * blockDim.x + threadIdx.x;
    int n = t >> SH;
    if (n >= M) return;
    int f = (t & ((1 << SH) - 1)) * 4;
    float s = dis[n];
    float s2 = s * s;
    size_t base = (size_t)n * F + f;
    float4 a = *(const float4*)&agg[base];
    float4 hv = *(const float4*)&h[base];
    float4 r;
    r.x = a.x + s2 * hv.x + b[f + 0];
    r.y = a.y + s2 * hv.y + b[f + 1];
    r.z = a.z + s2 * hv.z + b[f + 2];
    r.w = a.w + s2 * hv.w + b[f + 3];
    if (RELU) {
        r.x = fmaxf(r.x, 0.f); r.y = fmaxf(r.y, 0.f);
        r.z = fmaxf(r.z, 0.f); r.w = fmaxf(r.w, 0.f);
    }
    *(float4*)&h[base] = r;
}

// ---------------- final linear: [M,16] @ [16,7] + b -> out ----------------
__global__ __launch_bounds__(256) void final_linear_kernel(const float* __restrict__ h,
                                                           const float* __restrict__ Wl,
                                                           const float* __restrict__ bl,
                                                           float* __restrict__ out, int M) {
    __shared__ float Ws[112];
    __shared__ float bs[7];
    if (threadIdx.x < 112) Ws[threadIdx.x] = Wl[threadIdx.x];
    if (threadIdx.x < 7) bs[threadIdx.x] = bl[threadIdx.x];
    __syncthreads();
    int n = blockIdx.x * blockDim.x + threadIdx.x;
    if (n >= M) return;
    float hv[16];
    #pragma unroll
    for (int k = 0; k < 16; ++k) hv[k] = h[(size_t)n * 16 + k];
    #pragma unroll
    for (int o = 0; o < 7; ++o) {
        float acc = bs[o];
        #pragma unroll
        for (int k = 0; k < 16; ++k) acc += hv[k] * Ws[k * 7 + o];
        out[(size_t)n * 7 + o] = acc;
    }
}

extern "C" void kernel_launch(void* const* d_in, const int* in_sizes, int n_in,
                              void* d_out, int out_size, void* d_ws, size_t ws_size,
                              hipStream_t stream) {
    const float* x  = (const float*)d_in[0];
    const int* eidx = (const int*)d_in[1];
    const float* W1 = (const float*)d_in[2];
    const float* b1 = (const float*)d_in[3];
    const float* W2 = (const float*)d_in[4];
    const float* b2 = (const float*)d_in[5];
    const float* W3 = (const float*)d_in[6];
    const float* b3 = (const float*)d_in[7];
    const float* Wl = (const float*)d_in[8];
    const float* bl = (const float*)d_in[9];
    float* out = (float*)d_out;

    const int M = in_sizes[0] / 512;
    const int E = in_sizes[1] / 2;
    const int* src = eidx;
    const int* dst = eidx + E;

    char* ws = (char*)d_ws;
    int*   cnt = (int*)ws;                              // M ints
    float* dis = (float*)(ws + (1u << 20));             // M floats
    const size_t szH = ((size_t)M * 64 * sizeof(float) + 255) & ~(size_t)255;  // 25.6MB
    float* hA = (float*)(ws + (2u << 20));
    float* hB = (float*)(ws + (2u << 20) + szH);

    // degree + normalization
    hipMemsetAsync(cnt, 0, (size_t)M * sizeof(int), stream);
    count_dst_kernel<<<ceil_div_i(E, 256), 256, 0, stream>>>(dst, E, cnt);
    dis_kernel<<<ceil_div_i(M, 256), 256, 0, stream>>>(cnt, dis, M);

    // layer 1: 512 -> 64
    gemm1_kernel<<<ceil_div_i(M, 64), 256, 0, stream>>>(x, W1, hA, M);
    hipMemsetAsync(hB, 0, (size_t)M * 64 * sizeof(float), stream);
    scatter_kernel<64><<<ceil_div_i((long long)E * 16, 256), 256, 0, stream>>>(src, dst, dis, hA, hB, E);
    finalize_kernel<64, true><<<ceil_div_i((long long)M * 16, 256), 256, 0, stream>>>(hB, hA, dis, b1, M);

    // layer 2: 64 -> 32
    gemm_small_kernel<64, 32, 8><<<ceil_div_i(M, 8), 256, 0, stream>>>(hA, W2, hB, M);
    hipMemsetAsync(hA, 0, (size_t)M * 32 * sizeof(float), stream);
    scatter_kernel<32><<<ceil_div_i((long long)E * 8, 256), 256, 0, stream>>>(src, dst, dis, hB, hA, E);
    finalize_kernel<32, true><<<ceil_div_i((long long)M * 8, 256), 256, 0, stream>>>(hA, hB, dis, b2, M);

    // layer 3: 32 -> 16 (no relu)
    gemm_small_kernel<32, 16, 16><<<ceil_div_i(M, 16), 256, 0, stream>>>(hB, W3, hA, M);
    hipMemsetAsync(hB, 0, (size_t)M * 16 * sizeof(float), stream);
    scatter_kernel<16><<<ceil_div_i((long long)E * 4, 256), 256, 0, stream>>>(src, dst, dis, hA, hB, E);
    finalize_kernel<16, false><<<ceil_div_i((long long)M * 4, 256), 256, 0, stream>>>(hB, hA, dis, b3, M);

    // output head
    final_linear_kernel<<<ceil_div_i(M, 256), 256, 0, stream>>>(hA, Wl, bl, out, M);
}

// Round 2
// 540.149 us; speedup vs baseline: 4.7997x; 4.7997x over previous
//
#include <hip/hip_runtime.h>

// GCN 3-layer: x[N,512] -> GCNConv(512,64)+relu -> GCNConv(64,32)+relu ->
// GCNConv(32,16) -> Linear(16,7). Symmetric norm with self-loops.
// R2: CSR-by-dst built per call (counting sort), aggregation = fused gather
// (edges + self-loop + bias + relu) with register accumulation. No fp atomics.

static inline int ceil_div_i(long long a, long long b) { return (int)((a + b - 1) / b); }

// ---------------- degree ----------------
__global__ __launch_bounds__(256) void count_dst_kernel(const int* __restrict__ dst, int E,
                                                        int* __restrict__ cnt) {
    int i = blockIdx.x * blockDim.x + threadIdx.x;
    if (i < E) atomicAdd(&cnt[dst[i]], 1);
}

__global__ __launch_bounds__(256) void dis_kernel(const int* __restrict__ cnt,
                                                  float* __restrict__ dis, int M) {
    int i = blockIdx.x * blockDim.x + threadIdx.x;
    if (i < M) dis[i] = rsqrtf((float)(cnt[i] + 1));  // +1: self-loop
}

// ---------------- exclusive scan over cnt -> row_start[0..M] (one workgroup) ----------------
__global__ __launch_bounds__(1024) void scan_kernel(const int* __restrict__ cnt,
                                                    int* __restrict__ row_start, int M) {
    __shared__ int wsum[16];
    __shared__ int carry;
    const int t = threadIdx.x, lane = t & 63, wid = t >> 6;
    if (t == 0) carry = 0;
    __syncthreads();
    for (int base = 0; base <= M; base += 1024) {
        int i = base + t;
        int orig = (i < M) ? cnt[i] : 0;
        int v = orig;
        #pragma unroll
        for (int d = 1; d < 64; d <<= 1) {
            int o = __shfl_up(v, d);
            if (lane >= d) v += o;
        }
        if (lane == 63) wsum[wid] = v;
        __syncthreads();
        if (wid == 0) {
            int wv = (lane < 16) ? wsum[lane] : 0;
            #pragma unroll
            for (int d = 1; d < 16; d <<= 1) {
                int o = __shfl_up(wv, d);
                if (lane >= d) wv += o;
            }
            if (lane < 16) wsum[lane] = wv;  // inclusive scan of wave sums
        }
        __syncthreads();
        int wprefix = (wid > 0) ? wsum[wid - 1] : 0;
        int excl = carry + wprefix + (v - orig);
        if (i <= M) row_start[i] = excl;
        __syncthreads();
        if (t == 0) carry += wsum[15];
        __syncthreads();
    }
}

// ---------------- CSR fill: csr_src[row_start[d] + k] = src(e) ----------------
__global__ __launch_bounds__(256) void fill_kernel(const int* __restrict__ src,
                                                   const int* __restrict__ dst,
                                                   const int* __restrict__ row_start,
                                                   int* __restrict__ fill,
                                                   int* __restrict__ csr_src, int E) {
    int e = blockIdx.x * blockDim.x + threadIdx.x;
    if (e >= E) return;
    int d = dst[e];
    int pos = row_start[d] + atomicAdd(&fill[d], 1);
    csr_src[pos] = src[e];
}

// ---------------- GEMM1: [M,512] @ [512,64] -> [M,64] ----------------
__global__ __launch_bounds__(256) void gemm1_kernel(const float* __restrict__ x,
                                                    const float* __restrict__ W,
                                                    float* __restrict__ out, int M) {
    __shared__ float xs[64][36];
    __shared__ float ws[32][68];
    const int t = threadIdx.x;
    const int tx = t & 15;
    const int ty = t >> 4;
    const int m0 = blockIdx.x * 64;

    float acc[4][4] = {};
    for (int k0 = 0; k0 < 512; k0 += 32) {
        for (int i = t; i < 512; i += 256) {
            int r = i >> 3, c = (i & 7) * 4;
            int gm = m0 + r;
            float4 v = make_float4(0.f, 0.f, 0.f, 0.f);
            if (gm < M) v = *(const float4*)&x[(size_t)gm * 512 + k0 + c];
            xs[r][c] = v.x; xs[r][c + 1] = v.y; xs[r][c + 2] = v.z; xs[r][c + 3] = v.w;
        }
        for (int i = t; i < 512; i += 256) {
            int r = i >> 4, c = (i & 15) * 4;
            float4 v = *(const float4*)&W[(size_t)(k0 + r) * 64 + c];
            ws[r][c] = v.x; ws[r][c + 1] = v.y; ws[r][c + 2] = v.z; ws[r][c + 3] = v.w;
        }
        __syncthreads();
        #pragma unroll
        for (int kk = 0; kk < 32; ++kk) {
            float xv[4], wv[4];
            #pragma unroll
            for (int i = 0; i < 4; ++i) xv[i] = xs[ty * 4 + i][kk];
            #pragma unroll
            for (int j = 0; j < 4; ++j) wv[j] = ws[kk][tx * 4 + j];
            #pragma unroll
            for (int i = 0; i < 4; ++i)
                #pragma unroll
                for (int j = 0; j < 4; ++j) acc[i][j] += xv[i] * wv[j];
        }
        __syncthreads();
    }
    #pragma unroll
    for (int i = 0; i < 4; ++i) {
        int gm = m0 + ty * 4 + i;
        if (gm < M) {
            float4 v = make_float4(acc[i][0], acc[i][1], acc[i][2], acc[i][3]);
            *(float4*)&out[(size_t)gm * 64 + tx * 4] = v;
        }
    }
}

// ---------------- small GEMM: [M,K] @ [K,OUT] -> [M,OUT] ----------------
template <int K, int OUT, int NPB>
__global__ __launch_bounds__(256) void gemm_small_kernel(const float* __restrict__ h,
                                                         const float* __restrict__ W,
                                                         float* __restrict__ out, int M) {
    __shared__ float Ws[K * OUT];
    __shared__ float hs[NPB][K];
    const int t = threadIdx.x;
    for (int i = t; i < K * OUT; i += 256) Ws[i] = W[i];
    const int n0 = blockIdx.x * NPB;
    for (int i = t; i < NPB * K; i += 256) {
        int r = i / K, c = i % K;
        int gm = n0 + r;
        hs[r][c] = (gm < M) ? h[(size_t)gm * K + c] : 0.f;
    }
    __syncthreads();
    const int nl = t / OUT, o = t % OUT;
    float acc = 0.f;
    #pragma unroll
    for (int k = 0; k < K; ++k) acc += hs[nl][k] * Ws[k * OUT + o];
    int gm = n0 + nl;
    if (gm < M) out[(size_t)gm * OUT + o] = acc;
}

// ---------------- fused gather: o[n] = act( sum_e dis[s]dis[n] h[s] + dis[n]^2 h[n] + b ) ----
template <int F, bool RELU>
__global__ __launch_bounds__(256) void gather_kernel(const int* __restrict__ row_start,
                                                     const int* __restrict__ csr_src,
                                                     const float* __restrict__ dis,
                                                     const float* __restrict__ h,
                                                     const float* __restrict__ b,
                                                     float* __restrict__ o, int M) {
    constexpr int LPN = F / 4;  // lanes per node (float4 each)
    int t = blockIdx.x * blockDim.x + threadIdx.x;
    int n = t / LPN;
    if (n >= M) return;
    int f4 = (t % LPN) * 4;
    int rs = row_start[n], re = row_start[n + 1];
    float dn = dis[n];
    float4 acc = make_float4(0.f, 0.f, 0.f, 0.f);
    for (int i = rs; i < re; ++i) {
        int s = csr_src[i];
        float w = dis[s] * dn;
        float4 v = *(const float4*)&h[(size_t)s * F + f4];
        acc.x += w * v.x; acc.y += w * v.y; acc.z += w * v.z; acc.w += w * v.w;
    }
    float4 hv = *(const float4*)&h[(size_t)n * F + f4];
    float4 bv = *(const float4*)&b[f4];
    float s2 = dn * dn;
    acc.x += s2 * hv.x + bv.x;
    acc.y += s2 * hv.y + bv.y;
    acc.z += s2 * hv.z + bv.z;
    acc.w += s2 * hv.w + bv.w;
    if (RELU) {
        acc.x = fmaxf(acc.x, 0.f); acc.y = fmaxf(acc.y, 0.f);
        acc.z = fmaxf(acc.z, 0.f); acc.w = fmaxf(acc.w, 0.f);
    }
    *(float4*)&o[(size_t)n * F + f4] = acc;
}

// ---------------- final linear: [M,16] @ [16,7] + b -> out ----------------
__global__ __launch_bounds__(256) void final_linear_kernel(const float* __restrict__ h,
                                                           const float* __restrict__ Wl,
                                                           const float* __restrict__ bl,
                                                           float* __restrict__ out, int M) {
    __shared__ float Ws[112];
    __shared__ float bs[7];
    if (threadIdx.x < 112) Ws[threadIdx.x] = Wl[threadIdx.x];
    if (threadIdx.x < 7) bs[threadIdx.x] = bl[threadIdx.x];
    __syncthreads();
    int n = blockIdx.x * blockDim.x + threadIdx.x;
    if (n >= M) return;
    float hv[16];
    #pragma unroll
    for (int k = 0; k < 16; ++k) hv[k] = h[(size_t)n * 16 + k];
    #pragma unroll
    for (int o = 0; o < 7; ++o) {
        float acc = bs[o];
        #pragma unroll
        for (int k = 0; k < 16; ++k) acc += hv[k] * Ws[k * 7 + o];
        out[(size_t)n * 7 + o] = acc;
    }
}

extern "C" void kernel_launch(void* const* d_in, const int* in_sizes, int n_in,
                              void* d_out, int out_size, void* d_ws, size_t ws_size,
                              hipStream_t stream) {
    const float* x  = (const float*)d_in[0];
    const int* eidx = (const int*)d_in[1];
    const float* W1 = (const float*)d_in[2];
    const float* b1 = (const float*)d_in[3];
    const float* W2 = (const float*)d_in[4];
    const float* b2 = (const float*)d_in[5];
    const float* W3 = (const float*)d_in[6];
    const float* b3 = (const float*)d_in[7];
    const float* Wl = (const float*)d_in[8];
    const float* bl = (const float*)d_in[9];
    float* out = (float*)d_out;

    const int M = in_sizes[0] / 512;
    const int E = in_sizes[1] / 2;
    const int* src = eidx;
    const int* dst = eidx + E;

    // workspace layout (tight, ~59.3 MB)
    char* ws = (char*)d_ws;
    const size_t szM  = ((size_t)M * 4 + 255) & ~(size_t)255;        // 400KB
    const size_t szM1 = ((size_t)(M + 1) * 4 + 255) & ~(size_t)255;  // 400KB
    const size_t szE  = ((size_t)E * 4 + 255) & ~(size_t)255;        // 6.4MB
    const size_t szH  = ((size_t)M * 64 * 4 + 255) & ~(size_t)255;   // 25.6MB
    size_t off = 0;
    int*   cnt       = (int*)(ws + off); off += szM;
    float* dis       = (float*)(ws + off); off += szM;
    int*   row_start = (int*)(ws + off); off += szM1;
    int*   fill      = (int*)(ws + off); off += szM;
    int*   csr_src   = (int*)(ws + off); off += szE;
    float* hA        = (float*)(ws + off); off += szH;
    float* hB        = (float*)(ws + off); off += szH;

    // degree + norm + CSR build
    hipMemsetAsync(cnt, 0, (size_t)M * sizeof(int), stream);
    hipMemsetAsync(fill, 0, (size_t)M * sizeof(int), stream);
    count_dst_kernel<<<ceil_div_i(E, 256), 256, 0, stream>>>(dst, E, cnt);
    dis_kernel<<<ceil_div_i(M, 256), 256, 0, stream>>>(cnt, dis, M);
    scan_kernel<<<1, 1024, 0, stream>>>(cnt, row_start, M);
    fill_kernel<<<ceil_div_i(E, 256), 256, 0, stream>>>(src, dst, row_start, fill, csr_src, E);

    // layer 1: 512 -> 64
    gemm1_kernel<<<ceil_div_i(M, 64), 256, 0, stream>>>(x, W1, hA, M);
    gather_kernel<64, true><<<ceil_div_i((long long)M * 16, 256), 256, 0, stream>>>(
        row_start, csr_src, dis, hA, b1, hB, M);

    // layer 2: 64 -> 32
    gemm_small_kernel<64, 32, 8><<<ceil_div_i(M, 8), 256, 0, stream>>>(hB, W2, hA, M);
    gather_kernel<32, true><<<ceil_div_i((long long)M * 8, 256), 256, 0, stream>>>(
        row_start, csr_src, dis, hA, b2, hB, M);

    // layer 3: 32 -> 16 (no relu)
    gemm_small_kernel<32, 16, 16><<<ceil_div_i(M, 16), 256, 0, stream>>>(hB, W3, hA, M);
    gather_kernel<16, false><<<ceil_div_i((long long)M * 4, 256), 256, 0, stream>>>(
        row_start, csr_src, dis, hA, b3, hB, M);

    // output head
    final_linear_kernel<<<ceil_div_i(M, 256), 256, 0, stream>>>(hB, Wl, bl, out, M);
}

// Round 3
// 390.006 us; speedup vs baseline: 6.6475x; 1.3850x over previous
//
#include <hip/hip_runtime.h>

// GCN 3-layer on MI355X. R3:
//  - GEMM1 (100k x 512 @ 512 x 64) via bf16 MFMA 16x16x32, in-register RNE cvt.
//  - CSR build with 3-kernel hierarchical scan (was single-workgroup scan).
//  - Per-node GEMMs fused into the gather kernels (gather+bias+relu -> LDS -> @W).

typedef __bf16 bf16x8 __attribute__((ext_vector_type(8)));
typedef short short8v __attribute__((ext_vector_type(8)));
typedef float float4v __attribute__((ext_vector_type(4)));

static inline int ceil_div_i(long long a, long long b) { return (int)((a + b - 1) / b); }

__device__ inline unsigned short bf16rne(float f) {
    union { float f; unsigned u; } c; c.f = f;
    unsigned u = c.u;
    u += 0x7fffu + ((u >> 16) & 1u);
    return (unsigned short)(u >> 16);
}

// ---------------- degree / norm ----------------
__global__ __launch_bounds__(256) void count_dst_kernel(const int* __restrict__ dst, int E,
                                                        int* __restrict__ cnt) {
    int i = blockIdx.x * blockDim.x + threadIdx.x;
    if (i < E) atomicAdd(&cnt[dst[i]], 1);
}

__global__ __launch_bounds__(256) void dis_kernel(const int* __restrict__ cnt,
                                                  float* __restrict__ dis, int M) {
    int i = blockIdx.x * blockDim.x + threadIdx.x;
    if (i < M) dis[i] = rsqrtf((float)(cnt[i] + 1));  // +1: self-loop
}

// ---------------- hierarchical exclusive scan: cnt[M] -> row_start[M+1] ----------------
__global__ __launch_bounds__(256) void scan_reduce_kernel(const int* __restrict__ cnt,
                                                          int* __restrict__ partial, int M) {
    __shared__ int wsum_[4];
    int b = blockIdx.x, t = threadIdx.x, lane = t & 63, wid = t >> 6;
    int base = b * 1024 + t * 4;
    int s = 0;
    if (base + 3 < M) {
        int4 v = *(const int4*)&cnt[base];
        s = v.x + v.y + v.z + v.w;
    } else {
        for (int j = 0; j < 4; ++j)
            if (base + j < M) s += cnt[base + j];
    }
    #pragma unroll
    for (int d = 1; d < 64; d <<= 1) s += __shfl_xor(s, d);
    if (lane == 0) wsum_[wid] = s;
    __syncthreads();
    if (t == 0) partial[b] = wsum_[0] + wsum_[1] + wsum_[2] + wsum_[3];
}

__global__ __launch_bounds__(64) void scan_partials_kernel(int* __restrict__ partial, int nb) {
    int lane = threadIdx.x;
    int carry = 0;
    for (int base = 0; base < nb; base += 64) {
        int i = base + lane;
        int v = (i < nb) ? partial[i] : 0;
        int inc = v;
        #pragma unroll
        for (int d = 1; d < 64; d <<= 1) {
            int o = __shfl_up(inc, d);
            if (lane >= d) inc += o;
        }
        if (i < nb) partial[i] = carry + inc - v;  // exclusive
        carry += __shfl(inc, 63);
    }
}

__global__ __launch_bounds__(256) void scan_apply_kernel(const int* __restrict__ cnt,
                                                         const int* __restrict__ partial,
                                                         int* __restrict__ row_start, int M) {
    __shared__ int wsum_[4];
    int b = blockIdx.x, t = threadIdx.x, lane = t & 63, wid = t >> 6;
    int base = b * 1024 + t * 4;
    int4 v = {0, 0, 0, 0};
    if (base + 3 < M) {
        v = *(const int4*)&cnt[base];
    } else {
        v.x = (base + 0 < M) ? cnt[base + 0] : 0;
        v.y = (base + 1 < M) ? cnt[base + 1] : 0;
        v.z = (base + 2 < M) ? cnt[base + 2] : 0;
        v.w = (base + 3 < M) ? cnt[base + 3] : 0;
    }
    int s1 = v.x, s2 = s1 + v.y, s3 = s2 + v.z, s4 = s3 + v.w;
    int inc = s4;
    #pragma unroll
    for (int d = 1; d < 64; d <<= 1) {
        int o = __shfl_up(inc, d);
        if (lane >= d) inc += o;
    }
    if (lane == 63) wsum_[wid] = inc;
    __syncthreads();
    int wpre = 0;
    for (int ww = 0; ww < wid; ++ww) wpre += wsum_[ww];
    int excl = partial[b] + wpre + inc - s4;
    int outv[4] = {excl, excl + s1, excl + s2, excl + s3};
    #pragma unroll
    for (int j = 0; j < 4; ++j) {
        int idx = base + j;
        if (idx <= M) row_start[idx] = outv[j];  // row_start[M] = E lands here
    }
}

// ---------------- CSR fill ----------------
__global__ __launch_bounds__(256) void fill_kernel(const int* __restrict__ src,
                                                   const int* __restrict__ dst,
                                                   const int* __restrict__ row_start,
                                                   int* __restrict__ fill,
                                                   int* __restrict__ csr_src, int E) {
    int e = blockIdx.x * blockDim.x + threadIdx.x;
    if (e >= E) return;
    int d = dst[e];
    int pos = row_start[d] + atomicAdd(&fill[d], 1);
    csr_src[pos] = src[e];
}

// ---------------- W1 -> bf16 transposed [64][512] ----------------
__global__ __launch_bounds__(256) void w1t_kernel(const float* __restrict__ W1,
                                                  unsigned short* __restrict__ wt) {
    int i = blockIdx.x * 256 + threadIdx.x;  // 512*64 = 32768
    if (i >= 512 * 64) return;
    int k = i >> 6, n = i & 63;
    wt[(size_t)n * 512 + k] = bf16rne(W1[i]);
}

// ---------------- GEMM1 via MFMA: g1 = x @ W1, [M,512]@[512,64] ----------------
// Block 256 = 4 waves; wave w handles rows b*64 + w*16 .. +15, all 64 cols.
// A/B packed with identical bijective k-mapping (k = 8*(lane>>4) + slot) ->
// result invariant to HW K-permutation. C/D: col=lane&15, row=4*(lane>>4)+reg.
__global__ __launch_bounds__(256) void gemm1_mfma_kernel(const float* __restrict__ x,
                                                         const unsigned short* __restrict__ wt,
                                                         float* __restrict__ g1, int M) {
    const int t = threadIdx.x;
    const int w = t >> 6, l = t & 63;
    const int lr = l & 15, g = l >> 4;
    const int row = blockIdx.x * 64 + w * 16 + lr;
    const bool rok = row < M;
    float4v acc[4] = {};
    const float* xp = x + (size_t)row * 512 + g * 8;
    const unsigned short* wp = wt + (size_t)lr * 512 + g * 8;
    #pragma unroll 2
    for (int k0 = 0; k0 < 512; k0 += 32) {
        short8v av;
        if (rok) {
            float4 xa = *(const float4*)(xp + k0);
            float4 xb = *(const float4*)(xp + k0 + 4);
            av[0] = (short)bf16rne(xa.x); av[1] = (short)bf16rne(xa.y);
            av[2] = (short)bf16rne(xa.z); av[3] = (short)bf16rne(xa.w);
            av[4] = (short)bf16rne(xb.x); av[5] = (short)bf16rne(xb.y);
            av[6] = (short)bf16rne(xb.z); av[7] = (short)bf16rne(xb.w);
        } else {
            av = short8v{0, 0, 0, 0, 0, 0, 0, 0};
        }
        bf16x8 a = __builtin_bit_cast(bf16x8, av);
        #pragma unroll
        for (int f = 0; f < 4; ++f) {
            bf16x8 b = *(const bf16x8*)(wp + (size_t)f * 16 * 512 + k0);
            acc[f] = __builtin_amdgcn_mfma_f32_16x16x32_bf16(a, b, acc[f], 0, 0, 0);
        }
    }
    const int ro0 = blockIdx.x * 64 + w * 16 + 4 * g;
    #pragma unroll
    for (int f = 0; f < 4; ++f)
        #pragma unroll
        for (int r = 0; r < 4; ++r) {
            int ro = ro0 + r;
            if (ro < M) g1[(size_t)ro * 64 + f * 16 + lr] = acc[f][r];
        }
}

// ---------------- fused gather + per-node GEMM ----------------
// h[n] = act( sum_edges dis[s]dis[n] gin[s] + dis[n]^2 gin[n] + bin )   (in LDS)
// o[n] = h[n] @ W  (+ bout if FINAL)
template <int F, int FOUT, bool RELU, bool FINAL>
__global__ __launch_bounds__(256) void fused_gather_kernel(
        const int* __restrict__ row_start, const int* __restrict__ csr_src,
        const float* __restrict__ dis, const float* __restrict__ gin,
        const float* __restrict__ bin, const float* __restrict__ W,
        const float* __restrict__ bout, float* __restrict__ o, int M) {
    constexpr int LPN = F / 4;        // lanes per node
    constexpr int NPB = 256 / LPN;    // nodes per block
    __shared__ float Ws[F * FOUT];
    __shared__ float bs[FINAL ? FOUT : 1];
    __shared__ float hs[NPB][F + 4];
    const int t = threadIdx.x;
    for (int i = t; i < F * FOUT; i += 256) Ws[i] = W[i];
    if (FINAL && t < FOUT) bs[t] = bout[t];
    const int grp = t / LPN, f4 = (t % LPN) * 4;
    const int n = blockIdx.x * NPB + grp;
    if (n < M) {
        int rs = row_start[n], re = row_start[n + 1];
        float dn = dis[n];
        float4 acc = make_float4(0.f, 0.f, 0.f, 0.f);
        int i = rs;
        for (; i + 1 < re; i += 2) {  // 2-edge unroll for MLP
            int s0 = csr_src[i], s1 = csr_src[i + 1];
            float w0 = dis[s0] * dn, w1 = dis[s1] * dn;
            float4 v0 = *(const float4*)&gin[(size_t)s0 * F + f4];
            float4 v1 = *(const float4*)&gin[(size_t)s1 * F + f4];
            acc.x += w0 * v0.x + w1 * v1.x;
            acc.y += w0 * v0.y + w1 * v1.y;
            acc.z += w0 * v0.z + w1 * v1.z;
            acc.w += w0 * v0.w + w1 * v1.w;
        }
        if (i < re) {
            int s = csr_src[i];
            float wgt = dis[s] * dn;
            float4 v = *(const float4*)&gin[(size_t)s * F + f4];
            acc.x += wgt * v.x; acc.y += wgt * v.y;
            acc.z += wgt * v.z; acc.w += wgt * v.w;
        }
        float4 hv = *(const float4*)&gin[(size_t)n * F + f4];
        float4 bv = *(const float4*)&bin[f4];
        float s2 = dn * dn;
        acc.x += s2 * hv.x + bv.x;
        acc.y += s2 * hv.y + bv.y;
        acc.z += s2 * hv.z + bv.z;
        acc.w += s2 * hv.w + bv.w;
        if (RELU) {
            acc.x = fmaxf(acc.x, 0.f); acc.y = fmaxf(acc.y, 0.f);
            acc.z = fmaxf(acc.z, 0.f); acc.w = fmaxf(acc.w, 0.f);
        }
        hs[grp][f4 + 0] = acc.x; hs[grp][f4 + 1] = acc.y;
        hs[grp][f4 + 2] = acc.z; hs[grp][f4 + 3] = acc.w;
    }
    __syncthreads();
    for (int idx = t; idx < NPB * FOUT; idx += 256) {
        int nl = idx / FOUT, oc = idx % FOUT;
        int nn = blockIdx.x * NPB + nl;
        if (nn >= M) continue;
        float a = FINAL ? bs[oc] : 0.f;
        #pragma unroll
        for (int k = 0; k < F; ++k) a += hs[nl][k] * Ws[k * FOUT + oc];
        o[(size_t)nn * FOUT + oc] = a;
    }
}

extern "C" void kernel_launch(void* const* d_in, const int* in_sizes, int n_in,
                              void* d_out, int out_size, void* d_ws, size_t ws_size,
                              hipStream_t stream) {
    const float* x  = (const float*)d_in[0];
    const int* eidx = (const int*)d_in[1];
    const float* W1 = (const float*)d_in[2];
    const float* b1 = (const float*)d_in[3];
    const float* W2 = (const float*)d_in[4];
    const float* b2 = (const float*)d_in[5];
    const float* W3 = (const float*)d_in[6];
    const float* b3 = (const float*)d_in[7];
    const float* Wl = (const float*)d_in[8];
    const float* bl = (const float*)d_in[9];
    float* out = (float*)d_out;

    const int M = in_sizes[0] / 512;
    const int E = in_sizes[1] / 2;
    const int* src = eidx;
    const int* dst = eidx + E;

    // workspace layout (~52.9 MB)
    char* ws = (char*)d_ws;
    const size_t szM  = ((size_t)M * 4 + 255) & ~(size_t)255;
    const size_t szM1 = ((size_t)(M + 1) * 4 + 255) & ~(size_t)255;
    const size_t szE  = ((size_t)E * 4 + 255) & ~(size_t)255;
    size_t off = 0;
    int*   cnt       = (int*)(ws + off); off += szM;
    float* dis       = (float*)(ws + off); off += szM;
    int*   row_start = (int*)(ws + off); off += szM1;
    int*   fill      = (int*)(ws + off); off += szM;
    int*   csr_src   = (int*)(ws + off); off += szE;
    int*   partial   = (int*)(ws + off); off += 4096;           // scan partials
    unsigned short* wt = (unsigned short*)(ws + off); off += 66560;  // 64x512 bf16
    float* g1        = (float*)(ws + off); off += (size_t)M * 64 * 4; off = (off + 255) & ~(size_t)255;
    float* g2        = (float*)(ws + off); off += (size_t)M * 32 * 4; off = (off + 255) & ~(size_t)255;
    float* g3        = (float*)(ws + off); off += (size_t)M * 16 * 4;

    const int nbA = ceil_div_i((long long)M + 1, 1024);  // covers row_start[M]

    // degree + norm + CSR
    hipMemsetAsync(cnt, 0, (size_t)M * sizeof(int), stream);
    hipMemsetAsync(fill, 0, (size_t)M * sizeof(int), stream);
    count_dst_kernel<<<ceil_div_i(E, 256), 256, 0, stream>>>(dst, E, cnt);
    dis_kernel<<<ceil_div_i(M, 256), 256, 0, stream>>>(cnt, dis, M);
    scan_reduce_kernel<<<nbA, 256, 0, stream>>>(cnt, partial, M);
    scan_partials_kernel<<<1, 64, 0, stream>>>(partial, nbA);
    scan_apply_kernel<<<nbA, 256, 0, stream>>>(cnt, partial, row_start, M);
    fill_kernel<<<ceil_div_i(E, 256), 256, 0, stream>>>(src, dst, row_start, fill, csr_src, E);

    // layer 1 GEMM (MFMA)
    w1t_kernel<<<128, 256, 0, stream>>>(W1, wt);
    gemm1_mfma_kernel<<<ceil_div_i(M, 64), 256, 0, stream>>>(x, wt, g1, M);

    // fused layers
    fused_gather_kernel<64, 32, true, false><<<ceil_div_i(M, 16), 256, 0, stream>>>(
        row_start, csr_src, dis, g1, b1, W2, nullptr, g2, M);
    fused_gather_kernel<32, 16, true, false><<<ceil_div_i(M, 32), 256, 0, stream>>>(
        row_start, csr_src, dis, g2, b2, W3, nullptr, g3, M);
    fused_gather_kernel<16, 7, false, true><<<ceil_div_i(M, 64), 256, 0, stream>>>(
        row_start, csr_src, dis, g3, b3, Wl, bl, out, M);
}

// Round 4
// 362.288 us; speedup vs baseline: 7.1561x; 1.0765x over previous
//
#include <hip/hip_runtime.h>

// GCN 3-layer on MI355X. R4:
//  - CSR build via 2-pass bucket sort (dst>>9, 512-node buckets): LDS-histogram
//    scatter into bucketized abuf, then per-bucket LDS-cursor build of csr_src.
//    Replaces the random-write fill_kernel (107MB write-amp -> ~13MB).
//  - No hipMemsetAsync: custom zero kernel for cnt.
//  - dis fused into scan_apply.
//  - GEMM1 bf16 MFMA + fused gather+GEMM layers (unchanged from R3).

typedef __bf16 bf16x8 __attribute__((ext_vector_type(8)));
typedef short short8v __attribute__((ext_vector_type(8)));
typedef float float4v __attribute__((ext_vector_type(4)));

static inline int ceil_div_i(long long a, long long b) { return (int)((a + b - 1) / b); }

__device__ inline unsigned short bf16rne(float f) {
    union { float f; unsigned u; } c; c.f = f;
    unsigned u = c.u;
    u += 0x7fffu + ((u >> 16) & 1u);
    return (unsigned short)(u >> 16);
}

// ---------------- zero ints ----------------
__global__ __launch_bounds__(256) void zero_kernel(int* __restrict__ p, int n) {
    int i = blockIdx.x * blockDim.x + threadIdx.x;
    int4* p4 = (int4*)p;
    int n4 = n >> 2;
    for (int j = i; j < n4; j += gridDim.x * blockDim.x) p4[j] = make_int4(0, 0, 0, 0);
    if (i < (n & 3)) p[n4 * 4 + i] = 0;
}

// ---------------- degree ----------------
__global__ __launch_bounds__(256) void count_dst_kernel(const int* __restrict__ dst, int E,
                                                        int* __restrict__ cnt) {
    int i = blockIdx.x * blockDim.x + threadIdx.x;
    if (i < E) atomicAdd(&cnt[dst[i]], 1);
}

// ---------------- hierarchical exclusive scan: cnt[M] -> row_start[M+1] ----------------
__global__ __launch_bounds__(256) void scan_reduce_kernel(const int* __restrict__ cnt,
                                                          int* __restrict__ partial, int M) {
    __shared__ int wsum_[4];
    int b = blockIdx.x, t = threadIdx.x, lane = t & 63, wid = t >> 6;
    int base = b * 1024 + t * 4;
    int s = 0;
    if (base + 3 < M) {
        int4 v = *(const int4*)&cnt[base];
        s = v.x + v.y + v.z + v.w;
    } else {
        for (int j = 0; j < 4; ++j)
            if (base + j < M) s += cnt[base + j];
    }
    #pragma unroll
    for (int d = 1; d < 64; d <<= 1) s += __shfl_xor(s, d);
    if (lane == 0) wsum_[wid] = s;
    __syncthreads();
    if (t == 0) partial[b] = wsum_[0] + wsum_[1] + wsum_[2] + wsum_[3];
}

__global__ __launch_bounds__(64) void scan_partials_kernel(int* __restrict__ partial, int nb) {
    int lane = threadIdx.x;
    int carry = 0;
    for (int base = 0; base < nb; base += 64) {
        int i = base + lane;
        int v = (i < nb) ? partial[i] : 0;
        int inc = v;
        #pragma unroll
        for (int d = 1; d < 64; d <<= 1) {
            int o = __shfl_up(inc, d);
            if (lane >= d) inc += o;
        }
        if (i < nb) partial[i] = carry + inc - v;  // exclusive
        carry += __shfl(inc, 63);
    }
}

__global__ __launch_bounds__(256) void scan_apply_kernel(const int* __restrict__ cnt,
                                                         const int* __restrict__ partial,
                                                         int* __restrict__ row_start,
                                                         float* __restrict__ dis, int M) {
    __shared__ int wsum_[4];
    int b = blockIdx.x, t = threadIdx.x, lane = t & 63, wid = t >> 6;
    int base = b * 1024 + t * 4;
    int4 v = {0, 0, 0, 0};
    if (base + 3 < M) {
        v = *(const int4*)&cnt[base];
    } else {
        v.x = (base + 0 < M) ? cnt[base + 0] : 0;
        v.y = (base + 1 < M) ? cnt[base + 1] : 0;
        v.z = (base + 2 < M) ? cnt[base + 2] : 0;
        v.w = (base + 3 < M) ? cnt[base + 3] : 0;
    }
    // fused: dis = rsqrt(deg + self-loop)
    if (base + 0 < M) dis[base + 0] = rsqrtf((float)(v.x + 1));
    if (base + 1 < M) dis[base + 1] = rsqrtf((float)(v.y + 1));
    if (base + 2 < M) dis[base + 2] = rsqrtf((float)(v.z + 1));
    if (base + 3 < M) dis[base + 3] = rsqrtf((float)(v.w + 1));
    int s1 = v.x, s2 = s1 + v.y, s3 = s2 + v.z, s4 = s3 + v.w;
    int inc = s4;
    #pragma unroll
    for (int d = 1; d < 64; d <<= 1) {
        int o = __shfl_up(inc, d);
        if (lane >= d) inc += o;
    }
    if (lane == 63) wsum_[wid] = inc;
    __syncthreads();
    int wpre = 0;
    for (int ww = 0; ww < wid; ++ww) wpre += wsum_[ww];
    int excl = partial[b] + wpre + inc - s4;
    int outv[4] = {excl, excl + s1, excl + s2, excl + s3};
    #pragma unroll
    for (int j = 0; j < 4; ++j) {
        int idx = base + j;
        if (idx <= M) row_start[idx] = outv[j];  // row_start[M] = E sentinel
    }
}

// ---------------- CSR build pass 0: bucket cursors from row_start ----------------
__global__ __launch_bounds__(256) void init_gcur_kernel(const int* __restrict__ row_start,
                                                        int* __restrict__ gcur, int nb) {
    int t = threadIdx.x;
    if (t < nb) gcur[t] = row_start[t << 9];
}

// ---------------- CSR build pass 1: scatter edges into dst-buckets ----------------
// abuf[pos] = (dst&511)<<23 | src   (src < 2^23, M <= 131072 assumed)
__global__ __launch_bounds__(256) void bucket_scatter_kernel(const int* __restrict__ src,
                                                             const int* __restrict__ dst,
                                                             int* __restrict__ gcur,
                                                             unsigned* __restrict__ abuf, int E) {
    __shared__ int cur[256];
    const int t = threadIdx.x;
    const int e0 = blockIdx.x * 4096;
    const int e1 = min(e0 + 4096, E);
    cur[t] = 0;
    __syncthreads();
    for (int e = e0 + t; e < e1; e += 256) atomicAdd(&cur[dst[e] >> 9], 1);
    __syncthreads();
    int c = cur[t];
    cur[t] = c ? atomicAdd(&gcur[t], c) : 0;  // block's base within bucket region
    __syncthreads();
    for (int e = e0 + t; e < e1; e += 256) {
        int d = dst[e];
        int pos = atomicAdd(&cur[d >> 9], 1);
        abuf[pos] = ((unsigned)(d & 511) << 23) | (unsigned)src[e];
    }
}

// ---------------- CSR build pass 2: per-bucket ordered placement ----------------
__global__ __launch_bounds__(256) void csr_build_kernel(const int* __restrict__ row_start,
                                                        const unsigned* __restrict__ abuf,
                                                        int* __restrict__ csr_src, int M) {
    __shared__ int cur[512];
    const int b = blockIdx.x, t = threadIdx.x;
    const int n0 = b << 9;
    const int n1 = min(n0 + 512, M);
    for (int i = t; i < n1 - n0; i += 256) cur[i] = row_start[n0 + i];
    __syncthreads();
    const int s = row_start[n0], e = row_start[n1];
    for (int i = s + t; i < e; i += 256) {
        unsigned p = abuf[i];
        int pos = atomicAdd(&cur[p >> 23], 1);
        csr_src[pos] = (int)(p & 0x7fffffu);
    }
}

// ---------------- W1 -> bf16 transposed [64][512] ----------------
__global__ __launch_bounds__(256) void w1t_kernel(const float* __restrict__ W1,
                                                  unsigned short* __restrict__ wt) {
    int i = blockIdx.x * 256 + threadIdx.x;  // 512*64 = 32768
    if (i >= 512 * 64) return;
    int k = i >> 6, n = i & 63;
    wt[(size_t)n * 512 + k] = bf16rne(W1[i]);
}

// ---------------- GEMM1 via MFMA: g1 = x @ W1, [M,512]@[512,64] ----------------
__global__ __launch_bounds__(256) void gemm1_mfma_kernel(const float* __restrict__ x,
                                                         const unsigned short* __restrict__ wt,
                                                         float* __restrict__ g1, int M) {
    const int t = threadIdx.x;
    const int w = t >> 6, l = t & 63;
    const int lr = l & 15, g = l >> 4;
    const int row = blockIdx.x * 64 + w * 16 + lr;
    const bool rok = row < M;
    float4v acc[4] = {};
    const float* xp = x + (size_t)row * 512 + g * 8;
    const unsigned short* wp = wt + (size_t)lr * 512 + g * 8;
    #pragma unroll 2
    for (int k0 = 0; k0 < 512; k0 += 32) {
        short8v av;
        if (rok) {
            float4 xa = *(const float4*)(xp + k0);
            float4 xb = *(const float4*)(xp + k0 + 4);
            av[0] = (short)bf16rne(xa.x); av[1] = (short)bf16rne(xa.y);
            av[2] = (short)bf16rne(xa.z); av[3] = (short)bf16rne(xa.w);
            av[4] = (short)bf16rne(xb.x); av[5] = (short)bf16rne(xb.y);
            av[6] = (short)bf16rne(xb.z); av[7] = (short)bf16rne(xb.w);
        } else {
            av = short8v{0, 0, 0, 0, 0, 0, 0, 0};
        }
        bf16x8 a = __builtin_bit_cast(bf16x8, av);
        #pragma unroll
        for (int f = 0; f < 4; ++f) {
            bf16x8 b = *(const bf16x8*)(wp + (size_t)f * 16 * 512 + k0);
            acc[f] = __builtin_amdgcn_mfma_f32_16x16x32_bf16(a, b, acc[f], 0, 0, 0);
        }
    }
    const int ro0 = blockIdx.x * 64 + w * 16 + 4 * g;
    #pragma unroll
    for (int f = 0; f < 4; ++f)
        #pragma unroll
        for (int r = 0; r < 4; ++r) {
            int ro = ro0 + r;
            if (ro < M) g1[(size_t)ro * 64 + f * 16 + lr] = acc[f][r];
        }
}

// ---------------- fused gather + per-node GEMM ----------------
template <int F, int FOUT, bool RELU, bool FINAL>
__global__ __launch_bounds__(256) void fused_gather_kernel(
        const int* __restrict__ row_start, const int* __restrict__ csr_src,
        const float* __restrict__ dis, const float* __restrict__ gin,
        const float* __restrict__ bin, const float* __restrict__ W,
        const float* __restrict__ bout, float* __restrict__ o, int M) {
    constexpr int LPN = F / 4;        // lanes per node
    constexpr int NPB = 256 / LPN;    // nodes per block
    __shared__ float Ws[F * FOUT];
    __shared__ float bs[FINAL ? FOUT : 1];
    __shared__ float hs[NPB][F + 4];
    const int t = threadIdx.x;
    for (int i = t; i < F * FOUT; i += 256) Ws[i] = W[i];
    if (FINAL && t < FOUT) bs[t] = bout[t];
    const int grp = t / LPN, f4 = (t % LPN) * 4;
    const int n = blockIdx.x * NPB + grp;
    if (n < M) {
        int rs = row_start[n], re = row_start[n + 1];
        float dn = dis[n];
        float4 acc = make_float4(0.f, 0.f, 0.f, 0.f);
        int i = rs;
        for (; i + 1 < re; i += 2) {
            int s0 = csr_src[i], s1 = csr_src[i + 1];
            float w0 = dis[s0] * dn, w1 = dis[s1] * dn;
            float4 v0 = *(const float4*)&gin[(size_t)s0 * F + f4];
            float4 v1 = *(const float4*)&gin[(size_t)s1 * F + f4];
            acc.x += w0 * v0.x + w1 * v1.x;
            acc.y += w0 * v0.y + w1 * v1.y;
            acc.z += w0 * v0.z + w1 * v1.z;
            acc.w += w0 * v0.w + w1 * v1.w;
        }
        if (i < re) {
            int s = csr_src[i];
            float wgt = dis[s] * dn;
            float4 v = *(const float4*)&gin[(size_t)s * F + f4];
            acc.x += wgt * v.x; acc.y += wgt * v.y;
            acc.z += wgt * v.z; acc.w += wgt * v.w;
        }
        float4 hv = *(const float4*)&gin[(size_t)n * F + f4];
        float4 bv = *(const float4*)&bin[f4];
        float s2 = dn * dn;
        acc.x += s2 * hv.x + bv.x;
        acc.y += s2 * hv.y + bv.y;
        acc.z += s2 * hv.z + bv.z;
        acc.w += s2 * hv.w + bv.w;
        if (RELU) {
            acc.x = fmaxf(acc.x, 0.f); acc.y = fmaxf(acc.y, 0.f);
            acc.z = fmaxf(acc.z, 0.f); acc.w = fmaxf(acc.w, 0.f);
        }
        hs[grp][f4 + 0] = acc.x; hs[grp][f4 + 1] = acc.y;
        hs[grp][f4 + 2] = acc.z; hs[grp][f4 + 3] = acc.w;
    }
    __syncthreads();
    for (int idx = t; idx < NPB * FOUT; idx += 256) {
        int nl = idx / FOUT, oc = idx % FOUT;
        int nn = blockIdx.x * NPB + nl;
        if (nn >= M) continue;
        float a = FINAL ? bs[oc] : 0.f;
        #pragma unroll
        for (int k = 0; k < F; ++k) a += hs[nl][k] * Ws[k * FOUT + oc];
        o[(size_t)nn * FOUT + oc] = a;
    }
}

extern "C" void kernel_launch(void* const* d_in, const int* in_sizes, int n_in,
                              void* d_out, int out_size, void* d_ws, size_t ws_size,
                              hipStream_t stream) {
    const float* x  = (const float*)d_in[0];
    const int* eidx = (const int*)d_in[1];
    const float* W1 = (const float*)d_in[2];
    const float* b1 = (const float*)d_in[3];
    const float* W2 = (const float*)d_in[4];
    const float* b2 = (const float*)d_in[5];
    const float* W3 = (const float*)d_in[6];
    const float* b3 = (const float*)d_in[7];
    const float* Wl = (const float*)d_in[8];
    const float* bl = (const float*)d_in[9];
    float* out = (float*)d_out;

    const int M = in_sizes[0] / 512;
    const int E = in_sizes[1] / 2;
    const int* src = eidx;
    const int* dst = eidx + E;
    const int NB = ceil_div_i(M, 512);  // dst buckets (<=256 for M<=131072)

    // workspace layout (~60 MB)
    char* ws = (char*)d_ws;
    const size_t szM  = ((size_t)M * 4 + 255) & ~(size_t)255;
    const size_t szM1 = ((size_t)(M + 1) * 4 + 255) & ~(size_t)255;
    const size_t szE  = ((size_t)E * 4 + 255) & ~(size_t)255;
    size_t off = 0;
    int*      cnt       = (int*)(ws + off); off += szM;
    float*    dis       = (float*)(ws + off); off += szM;
    int*      row_start = (int*)(ws + off); off += szM1;
    int*      gcur      = (int*)(ws + off); off += 4096;
    int*      partial   = (int*)(ws + off); off += 4096;
    int*      csr_src   = (int*)(ws + off); off += szE;
    unsigned* abuf      = (unsigned*)(ws + off); off += szE;
    unsigned short* wt  = (unsigned short*)(ws + off); off += 66560;  // 64x512 bf16
    float* g1 = (float*)(ws + off); off += (size_t)M * 64 * 4; off = (off + 255) & ~(size_t)255;
    float* g2 = (float*)(ws + off); off += (size_t)M * 32 * 4; off = (off + 255) & ~(size_t)255;
    float* g3 = (float*)(ws + off); off += (size_t)M * 16 * 4;

    const int nbA = ceil_div_i((long long)M + 1, 1024);

    // degree + norm + CSR (bucketized, no fp or random-write scatters)
    zero_kernel<<<98, 256, 0, stream>>>(cnt, M);
    count_dst_kernel<<<ceil_div_i(E, 256), 256, 0, stream>>>(dst, E, cnt);
    scan_reduce_kernel<<<nbA, 256, 0, stream>>>(cnt, partial, M);
    scan_partials_kernel<<<1, 64, 0, stream>>>(partial, nbA);
    scan_apply_kernel<<<nbA, 256, 0, stream>>>(cnt, partial, row_start, dis, M);
    init_gcur_kernel<<<1, 256, 0, stream>>>(row_start, gcur, NB);
    bucket_scatter_kernel<<<ceil_div_i(E, 4096), 256, 0, stream>>>(src, dst, gcur, abuf, E);
    csr_build_kernel<<<NB, 256, 0, stream>>>(row_start, abuf, csr_src, M);

    // layer 1 GEMM (MFMA)
    w1t_kernel<<<128, 256, 0, stream>>>(W1, wt);
    gemm1_mfma_kernel<<<ceil_div_i(M, 64), 256, 0, stream>>>(x, wt, g1, M);

    // fused layers
    fused_gather_kernel<64, 32, true, false><<<ceil_div_i(M, 16), 256, 0, stream>>>(
        row_start, csr_src, dis, g1, b1, W2, nullptr, g2, M);
    fused_gather_kernel<32, 16, true, false><<<ceil_div_i(M, 32), 256, 0, stream>>>(
        row_start, csr_src, dis, g2, b2, W3, nullptr, g3, M);
    fused_gather_kernel<16, 7, false, true><<<ceil_div_i(M, 64), 256, 0, stream>>>(
        row_start, csr_src, dis, g3, b3, Wl, bl, out, M);
}

// Round 5
// 257.404 us; speedup vs baseline: 10.0720x; 1.4075x over previous
//
#include <hip/hip_runtime.h>

// GCN 3-layer on MI355X. R5:
//  - CSR pipeline: bucket-hist -> 1-block scan -> bucket scatter -> per-bucket
//    rowstart+dis -> per-bucket place with PRECOMPUTED edge weight (src,w) int2.
//  - g1 stored bf16 (halves gather-1 traffic).
//  - Gathers: LPN-lane groups share edges via __shfl(width) (1 edge-load per
//    LPN lanes), zero-padded tail batches, register-tiled MLP (float4 Ws).

typedef __bf16 bf16x8 __attribute__((ext_vector_type(8)));
typedef short short8v __attribute__((ext_vector_type(8)));
typedef unsigned short ushort8v __attribute__((ext_vector_type(8)));
typedef float float4v __attribute__((ext_vector_type(4)));

static inline int ceil_div_i(long long a, long long b) { return (int)((a + b - 1) / b); }

__device__ inline unsigned short bf16rne(float f) {
    union { float f; unsigned u; } c; c.f = f;
    unsigned u = c.u;
    u += 0x7fffu + ((u >> 16) & 1u);
    return (unsigned short)(u >> 16);
}

// ---------------- CSR pass 1: bucket histogram (dst>>9) ----------------
__global__ __launch_bounds__(256) void bhist_kernel(const int* __restrict__ dst, int E,
                                                    int* __restrict__ bucket_cnt) {
    __shared__ int h[256];
    const int t = threadIdx.x;
    h[t] = 0;
    __syncthreads();
    const int e0 = blockIdx.x * 4096;
    const int e1 = min(e0 + 4096, E);
    for (int e = e0 + t; e < e1; e += 256) atomicAdd(&h[dst[e] >> 9], 1);
    __syncthreads();
    if (h[t]) atomicAdd(&bucket_cnt[t], h[t]);
}

// ---------------- CSR pass 2: scan bucket counts -> bases + cursors ----------------
__global__ __launch_bounds__(256) void bscan_kernel(const int* __restrict__ bucket_cnt,
                                                    int* __restrict__ bb,
                                                    int* __restrict__ gcur,
                                                    int* __restrict__ row_start,
                                                    int NB, int M, int E) {
    __shared__ int wsum_[4];
    const int t = threadIdx.x, lane = t & 63, wid = t >> 6;
    int v = (t < NB) ? bucket_cnt[t] : 0;
    int inc = v;
    #pragma unroll
    for (int d = 1; d < 64; d <<= 1) {
        int o = __shfl_up(inc, d);
        if (lane >= d) inc += o;
    }
    if (lane == 63) wsum_[wid] = inc;
    __syncthreads();
    int wpre = 0;
    for (int ww = 0; ww < wid; ++ww) wpre += wsum_[ww];
    int excl = wpre + inc - v;
    if (t < NB) { bb[t] = excl; gcur[t] = excl; }
    if (t == 0) { bb[NB] = E; row_start[M] = E; }
}

// ---------------- CSR pass 3: scatter edges into dst-buckets ----------------
// abuf[pos] = (dst&511)<<23 | src   (needs M < 2^23)
__global__ __launch_bounds__(256) void bucket_scatter_kernel(const int* __restrict__ src,
                                                             const int* __restrict__ dst,
                                                             int* __restrict__ gcur,
                                                             unsigned* __restrict__ abuf, int E) {
    __shared__ int cur[256];
    const int t = threadIdx.x;
    const int e0 = blockIdx.x * 4096;
    const int e1 = min(e0 + 4096, E);
    cur[t] = 0;
    __syncthreads();
    for (int e = e0 + t; e < e1; e += 256) atomicAdd(&cur[dst[e] >> 9], 1);
    __syncthreads();
    int c = cur[t];
    cur[t] = c ? atomicAdd(&gcur[t], c) : 0;
    __syncthreads();
    for (int e = e0 + t; e < e1; e += 256) {
        int d = dst[e];
        int pos = atomicAdd(&cur[d >> 9], 1);
        abuf[pos] = ((unsigned)(d & 511) << 23) | (unsigned)src[e];
    }
}

// ---------------- CSR pass 4: per-bucket local hist+scan -> row_start, dis ----------------
__global__ __launch_bounds__(256) void rowdis_kernel(const int* __restrict__ bb,
                                                     const unsigned* __restrict__ abuf,
                                                     int* __restrict__ row_start,
                                                     float* __restrict__ dis, int M) {
    __shared__ int hist[512];
    __shared__ int wsum_[4];
    const int b = blockIdx.x, t = threadIdx.x, lane = t & 63, wid = t >> 6;
    const int n0 = b << 9;
    hist[t] = 0; hist[t + 256] = 0;
    __syncthreads();
    const int s = bb[b], e = bb[b + 1];
    for (int i = s + t; i < e; i += 256) atomicAdd(&hist[abuf[i] >> 23], 1);
    __syncthreads();
    int c0 = hist[2 * t], c1 = hist[2 * t + 1];
    int pair = c0 + c1;
    int inc = pair;
    #pragma unroll
    for (int d = 1; d < 64; d <<= 1) {
        int o = __shfl_up(inc, d);
        if (lane >= d) inc += o;
    }
    if (lane == 63) wsum_[wid] = inc;
    __syncthreads();
    int wpre = 0;
    for (int ww = 0; ww < wid; ++ww) wpre += wsum_[ww];
    int excl = wpre + inc - pair;  // exclusive over pairs
    int r0 = s + excl, r1 = r0 + c0;
    int n = n0 + 2 * t;
    if (n < M)     { row_start[n] = r0;     dis[n] = rsqrtf((float)(c0 + 1)); }
    if (n + 1 < M) { row_start[n + 1] = r1; dis[n + 1] = rsqrtf((float)(c1 + 1)); }
}

// ---------------- CSR pass 5: place edges with precomputed weight ----------------
__global__ __launch_bounds__(256) void place_kernel(const int* __restrict__ bb,
                                                    const unsigned* __restrict__ abuf,
                                                    const int* __restrict__ row_start,
                                                    const float* __restrict__ dis,
                                                    int2* __restrict__ ew, int M) {
    __shared__ int cur[512];
    __shared__ float disl[512];
    const int b = blockIdx.x, t = threadIdx.x;
    const int n0 = b << 9;
    for (int i = t; i < 512; i += 256) {
        int n = n0 + i;
        cur[i] = (n < M) ? row_start[n] : 0;
        disl[i] = (n < M) ? dis[n] : 0.f;
    }
    __syncthreads();
    const int s = bb[b], e = bb[b + 1];
    for (int i = s + t; i < e; i += 256) {
        unsigned p = abuf[i];
        int ld = p >> 23;
        int sr = (int)(p & 0x7fffffu);
        float w = dis[sr] * disl[ld];
        int pos = atomicAdd(&cur[ld], 1);
        ew[pos] = make_int2(sr, __float_as_int(w));
    }
}

// ---------------- W1 -> bf16 transposed [64][512] ----------------
__global__ __launch_bounds__(256) void w1t_kernel(const float* __restrict__ W1,
                                                  unsigned short* __restrict__ wt) {
    int i = blockIdx.x * 256 + threadIdx.x;
    if (i >= 512 * 64) return;
    int k = i >> 6, n = i & 63;
    wt[(size_t)n * 512 + k] = bf16rne(W1[i]);
}

// ---------------- GEMM1 via MFMA: g1(bf16) = x @ W1, [M,512]@[512,64] ----------------
__global__ __launch_bounds__(256) void gemm1_mfma_kernel(const float* __restrict__ x,
                                                         const unsigned short* __restrict__ wt,
                                                         unsigned short* __restrict__ g1, int M) {
    const int t = threadIdx.x;
    const int w = t >> 6, l = t & 63;
    const int lr = l & 15, g = l >> 4;
    const int row = blockIdx.x * 64 + w * 16 + lr;
    const bool rok = row < M;
    float4v acc[4] = {};
    const float* xp = x + (size_t)row * 512 + g * 8;
    const unsigned short* wp = wt + (size_t)lr * 512 + g * 8;
    #pragma unroll 2
    for (int k0 = 0; k0 < 512; k0 += 32) {
        short8v av;
        if (rok) {
            float4 xa = *(const float4*)(xp + k0);
            float4 xb = *(const float4*)(xp + k0 + 4);
            av[0] = (short)bf16rne(xa.x); av[1] = (short)bf16rne(xa.y);
            av[2] = (short)bf16rne(xa.z); av[3] = (short)bf16rne(xa.w);
            av[4] = (short)bf16rne(xb.x); av[5] = (short)bf16rne(xb.y);
            av[6] = (short)bf16rne(xb.z); av[7] = (short)bf16rne(xb.w);
        } else {
            av = short8v{0, 0, 0, 0, 0, 0, 0, 0};
        }
        bf16x8 a = __builtin_bit_cast(bf16x8, av);
        #pragma unroll
        for (int f = 0; f < 4; ++f) {
            bf16x8 b = *(const bf16x8*)(wp + (size_t)f * 16 * 512 + k0);
            acc[f] = __builtin_amdgcn_mfma_f32_16x16x32_bf16(a, b, acc[f], 0, 0, 0);
        }
    }
    const int ro0 = blockIdx.x * 64 + w * 16 + 4 * g;
    #pragma unroll
    for (int f = 0; f < 4; ++f)
        #pragma unroll
        for (int r = 0; r < 4; ++r) {
            int ro = ro0 + r;
            if (ro < M) g1[(size_t)ro * 64 + f * 16 + lr] = bf16rne(acc[f][r]);
        }
}

// ---------------- fused gather + MLP ----------------
// agg = sum_edges w_e * gin[s] (+ dis[n]^2 * gin[n]); h = act(agg + bin);
// o[n] = h @ W (+bout if FINAL). LPN lanes per node share edges via shfl.
template <int F, int FOUT, int LPN, bool RELU, bool FINAL, bool BF16IN>
__global__ __launch_bounds__(256) void gather_mlp_kernel(
        const int* __restrict__ row_start, const int2* __restrict__ ew,
        const float* __restrict__ dis, const void* __restrict__ gin_,
        const float* __restrict__ bin, const float* __restrict__ W,
        const float* __restrict__ bout, float* __restrict__ o, int M) {
    constexpr int VEC = F / LPN;      // 8 (bf16) or 4 (f32)
    constexpr int NPB = 256 / LPN;    // nodes per block
    __shared__ float Ws[F * FOUT];
    __shared__ float hs[NPB][F + 4];
    __shared__ float bs[FINAL ? FOUT : 1];
    const int t = threadIdx.x;
    for (int i = t; i < F * FOUT; i += 256) Ws[i] = W[i];
    if (FINAL && t < FOUT) bs[t] = bout[t];
    const int grp = t / LPN, gl = t % LPN;
    const int n = blockIdx.x * NPB + grp;
    if (n < M) {
        const int rs = row_start[n], re = row_start[n + 1];
        float acc[VEC] = {};
        int i = rs;
        while (i < re) {
            int take = re - i;
            int s = 0; float wgt = 0.f;
            if (gl < take) {
                int2 epk = ew[i + gl];
                s = epk.x; wgt = __int_as_float(epk.y);
            }
            #pragma unroll
            for (int jj = 0; jj < LPN; ++jj) {   // zero-w padded: full unroll
                int sj = __shfl(s, jj, LPN);
                float wj = __shfl(wgt, jj, LPN);
                if (BF16IN) {
                    ushort8v r8 = *(const ushort8v*)((const unsigned short*)gin_ +
                                                     (size_t)sj * F + gl * VEC);
                    #pragma unroll
                    for (int k = 0; k < VEC; ++k)
                        acc[k] += wj * __uint_as_float((unsigned)r8[k] << 16);
                } else {
                    float4 v = *(const float4*)((const float*)gin_ +
                                                (size_t)sj * F + gl * VEC);
                    acc[0] += wj * v.x; acc[1] += wj * v.y;
                    acc[2] += wj * v.z; acc[3] += wj * v.w;
                }
            }
            i += LPN;
        }
        // self-loop + bias (+relu)
        float dn = dis[n], w2 = dn * dn;
        if (BF16IN) {
            ushort8v r8 = *(const ushort8v*)((const unsigned short*)gin_ +
                                             (size_t)n * F + gl * VEC);
            #pragma unroll
            for (int k = 0; k < VEC; ++k)
                acc[k] += w2 * __uint_as_float((unsigned)r8[k] << 16);
        } else {
            float4 v = *(const float4*)((const float*)gin_ + (size_t)n * F + gl * VEC);
            acc[0] += w2 * v.x; acc[1] += w2 * v.y;
            acc[2] += w2 * v.z; acc[3] += w2 * v.w;
        }
        #pragma unroll
        for (int k = 0; k < VEC; ++k) {
            float r = acc[k] + bin[gl * VEC + k];
            if (RELU) r = fmaxf(r, 0.f);
            hs[grp][gl * VEC + k] = r;
        }
    }
    __syncthreads();
    // MLP: h[F] @ W[F][FOUT]
    if (!FINAL) {
        constexpr int OCPT = FOUT / LPN;  // 4 (32/8) or 2 (16/8)
        if (n < M) {
            const int oc0 = gl * OCPT;
            float a[OCPT] = {};
            #pragma unroll
            for (int k = 0; k < F; ++k) {
                float hv = hs[grp][k];
                if (OCPT == 4) {
                    float4 wv = *(const float4*)&Ws[k * FOUT + oc0];
                    a[0] += hv * wv.x; a[1] += hv * wv.y;
                    a[2] += hv * wv.z; a[3] += hv * wv.w;
                } else {
                    float2 wv = *(const float2*)&Ws[k * FOUT + oc0];
                    a[0] += hv * wv.x; a[1] += hv * wv.y;
                }
            }
            #pragma unroll
            for (int j = 0; j < OCPT; ++j) o[(size_t)n * FOUT + oc0 + j] = a[j];
        }
    } else {
        for (int idx = t; idx < NPB * FOUT; idx += 256) {
            int nl = idx / FOUT, oc = idx % FOUT;
            int nn = blockIdx.x * NPB + nl;
            if (nn >= M) continue;
            float a = bs[oc];
            #pragma unroll
            for (int k = 0; k < F; ++k) a += hs[nl][k] * Ws[k * FOUT + oc];
            o[(size_t)nn * FOUT + oc] = a;
        }
    }
}

extern "C" void kernel_launch(void* const* d_in, const int* in_sizes, int n_in,
                              void* d_out, int out_size, void* d_ws, size_t ws_size,
                              hipStream_t stream) {
    const float* x  = (const float*)d_in[0];
    const int* eidx = (const int*)d_in[1];
    const float* W1 = (const float*)d_in[2];
    const float* b1 = (const float*)d_in[3];
    const float* W2 = (const float*)d_in[4];
    const float* b2 = (const float*)d_in[5];
    const float* W3 = (const float*)d_in[6];
    const float* b3 = (const float*)d_in[7];
    const float* Wl = (const float*)d_in[8];
    const float* bl = (const float*)d_in[9];
    float* out = (float*)d_out;

    const int M = in_sizes[0] / 512;
    const int E = in_sizes[1] / 2;
    const int* src = eidx;
    const int* dst = eidx + E;
    const int NB = ceil_div_i(M, 512);  // <=256 for M<=131072

    // workspace (~52 MB)
    char* ws = (char*)d_ws;
    const size_t szM1 = ((size_t)(M + 1) * 4 + 255) & ~(size_t)255;
    const size_t szE  = ((size_t)E * 4 + 255) & ~(size_t)255;
    size_t off = 0;
    int*      bucket_cnt = (int*)(ws + off); off += 2048;
    int*      bb         = (int*)(ws + off); off += 2048;
    int*      gcur       = (int*)(ws + off); off += 2048;
    int*      row_start  = (int*)(ws + off); off += szM1;
    float*    dis        = (float*)(ws + off); off += szM1;
    unsigned* abuf       = (unsigned*)(ws + off); off += szE;
    int2*     ew         = (int2*)(ws + off); off += 2 * szE;
    unsigned short* wt   = (unsigned short*)(ws + off); off += 66560;
    unsigned short* g1   = (unsigned short*)(ws + off);
    off += ((size_t)M * 64 * 2 + 255) & ~(size_t)255;
    float* g2 = (float*)(ws + off); off += (size_t)M * 32 * 4; off = (off + 255) & ~(size_t)255;
    float* g3 = (float*)(ws + off); off += (size_t)M * 16 * 4;

    const int EB = ceil_div_i(E, 4096);

    // CSR build (5 kernels, no fp atomics, bucketized writes)
    hipMemsetAsync(bucket_cnt, 0, 1024, stream);
    bhist_kernel<<<EB, 256, 0, stream>>>(dst, E, bucket_cnt);
    bscan_kernel<<<1, 256, 0, stream>>>(bucket_cnt, bb, gcur, row_start, NB, M, E);
    bucket_scatter_kernel<<<EB, 256, 0, stream>>>(src, dst, gcur, abuf, E);
    rowdis_kernel<<<NB, 256, 0, stream>>>(bb, abuf, row_start, dis, M);
    place_kernel<<<NB, 256, 0, stream>>>(bb, abuf, row_start, dis, ew, M);

    // layer 1 GEMM (MFMA, bf16 out)
    w1t_kernel<<<128, 256, 0, stream>>>(W1, wt);
    gemm1_mfma_kernel<<<ceil_div_i(M, 64), 256, 0, stream>>>(x, wt, g1, M);

    // fused gather+MLP layers
    gather_mlp_kernel<64, 32, 8, true, false, true><<<ceil_div_i(M, 32), 256, 0, stream>>>(
        row_start, ew, dis, g1, b1, W2, nullptr, g2, M);
    gather_mlp_kernel<32, 16, 8, true, false, false><<<ceil_div_i(M, 32), 256, 0, stream>>>(
        row_start, ew, dis, g2, b2, W3, nullptr, g3, M);
    gather_mlp_kernel<16, 7, 4, false, true, false><<<ceil_div_i(M, 64), 256, 0, stream>>>(
        row_start, ew, dis, g3, b3, Wl, bl, out, M);
}

// Round 6
// 246.680 us; speedup vs baseline: 10.5098x; 1.0435x over previous
//
#include <hip/hip_runtime.h>

// GCN 3-layer on MI355X. R6:
//  - CSR: bhist(+w1t fused) -> bscan -> bucket_scatter -> build (hist+scan+
//    dis+place in ONE kernel). csr_src stores src only; edge weight computed
//    in gather from L2-resident dis[] (no ew array).
//  - g1, g2 bf16 (g3 f32 to protect error budget).
//  - 9 dispatches total.

typedef __bf16 bf16x8 __attribute__((ext_vector_type(8)));
typedef short short8v __attribute__((ext_vector_type(8)));
typedef unsigned short ushort8v __attribute__((ext_vector_type(8)));
typedef unsigned short ushort4v __attribute__((ext_vector_type(4)));
typedef float float4v __attribute__((ext_vector_type(4)));

static inline int ceil_div_i(long long a, long long b) { return (int)((a + b - 1) / b); }

__device__ inline unsigned short bf16rne(float f) {
    union { float f; unsigned u; } c; c.f = f;
    unsigned u = c.u;
    u += 0x7fffu + ((u >> 16) & 1u);
    return (unsigned short)(u >> 16);
}
__device__ inline float bf16tof(unsigned short h) {
    return __uint_as_float((unsigned)h << 16);
}

// ---------------- pass 1: bucket histogram (dst>>9) + W1 transpose ----------------
__global__ __launch_bounds__(256) void bhist_w1t_kernel(const int* __restrict__ dst, int E,
                                                        int* __restrict__ bucket_cnt, int EB,
                                                        const float* __restrict__ W1,
                                                        unsigned short* __restrict__ wt) {
    const int t = threadIdx.x;
    if (blockIdx.x >= EB) {  // w1t part: 128 blocks
        int i = (blockIdx.x - EB) * 256 + t;
        if (i < 512 * 64) {
            int k = i >> 6, n = i & 63;
            wt[(size_t)n * 512 + k] = bf16rne(W1[i]);
        }
        return;
    }
    __shared__ int h[256];
    h[t] = 0;
    __syncthreads();
    const int e0 = blockIdx.x * 4096;
    const int e1 = min(e0 + 4096, E);
    for (int e = e0 + t; e < e1; e += 256) atomicAdd(&h[dst[e] >> 9], 1);
    __syncthreads();
    if (h[t]) atomicAdd(&bucket_cnt[t], h[t]);
}

// ---------------- pass 2: scan bucket counts -> bases + cursors ----------------
__global__ __launch_bounds__(256) void bscan_kernel(const int* __restrict__ bucket_cnt,
                                                    int* __restrict__ bb,
                                                    int* __restrict__ gcur,
                                                    int* __restrict__ row_start,
                                                    int NB, int M, int E) {
    __shared__ int wsum_[4];
    const int t = threadIdx.x, lane = t & 63, wid = t >> 6;
    int v = (t < NB) ? bucket_cnt[t] : 0;
    int inc = v;
    #pragma unroll
    for (int d = 1; d < 64; d <<= 1) {
        int o = __shfl_up(inc, d);
        if (lane >= d) inc += o;
    }
    if (lane == 63) wsum_[wid] = inc;
    __syncthreads();
    int wpre = 0;
    for (int ww = 0; ww < wid; ++ww) wpre += wsum_[ww];
    int excl = wpre + inc - v;
    if (t < NB) { bb[t] = excl; gcur[t] = excl; }
    if (t == 0) { bb[NB] = E; row_start[M] = E; }
}

// ---------------- pass 3: scatter edges into dst-buckets ----------------
// abuf[pos] = (dst&511)<<23 | src   (needs M < 2^23)
__global__ __launch_bounds__(256) void bucket_scatter_kernel(const int* __restrict__ src,
                                                             const int* __restrict__ dst,
                                                             int* __restrict__ gcur,
                                                             unsigned* __restrict__ abuf, int E) {
    __shared__ int cur[256];
    const int t = threadIdx.x;
    const int e0 = blockIdx.x * 4096;
    const int e1 = min(e0 + 4096, E);
    cur[t] = 0;
    __syncthreads();
    for (int e = e0 + t; e < e1; e += 256) atomicAdd(&cur[dst[e] >> 9], 1);
    __syncthreads();
    int c = cur[t];
    cur[t] = c ? atomicAdd(&gcur[t], c) : 0;
    __syncthreads();
    for (int e = e0 + t; e < e1; e += 256) {
        int d = dst[e];
        int pos = atomicAdd(&cur[d >> 9], 1);
        abuf[pos] = ((unsigned)(d & 511) << 23) | (unsigned)src[e];
    }
}

// ---------------- pass 4: per-bucket hist + scan -> row_start/dis, then place ----------------
__global__ __launch_bounds__(256) void build_kernel(const int* __restrict__ bb,
                                                    const unsigned* __restrict__ abuf,
                                                    int* __restrict__ row_start,
                                                    float* __restrict__ dis,
                                                    int* __restrict__ csr_src, int M) {
    __shared__ int hist[512];
    __shared__ int cur[512];
    __shared__ int wsum_[4];
    const int b = blockIdx.x, t = threadIdx.x, lane = t & 63, wid = t >> 6;
    const int n0 = b << 9;
    hist[t] = 0; hist[t + 256] = 0;
    __syncthreads();
    const int s = bb[b], e = bb[b + 1];
    for (int i = s + t; i < e; i += 256) atomicAdd(&hist[abuf[i] >> 23], 1);
    __syncthreads();
    int c0 = hist[2 * t], c1 = hist[2 * t + 1];
    int pair = c0 + c1;
    int inc = pair;
    #pragma unroll
    for (int d = 1; d < 64; d <<= 1) {
        int o = __shfl_up(inc, d);
        if (lane >= d) inc += o;
    }
    if (lane == 63) wsum_[wid] = inc;
    __syncthreads();
    int wpre = 0;
    for (int ww = 0; ww < wid; ++ww) wpre += wsum_[ww];
    int excl = wpre + inc - pair;  // exclusive over pairs
    int r0 = s + excl, r1 = r0 + c0;
    int n = n0 + 2 * t;
    if (n < M)     { row_start[n] = r0;     dis[n] = rsqrtf((float)(c0 + 1)); }
    if (n + 1 < M) { row_start[n + 1] = r1; dis[n + 1] = rsqrtf((float)(c1 + 1)); }
    cur[2 * t] = r0; cur[2 * t + 1] = r1;
    __syncthreads();
    for (int i = s + t; i < e; i += 256) {
        unsigned p = abuf[i];
        int pos = atomicAdd(&cur[p >> 23], 1);
        csr_src[pos] = (int)(p & 0x7fffffu);
    }
}

// ---------------- GEMM1 via MFMA: g1(bf16) = x @ W1, [M,512]@[512,64] ----------------
__global__ __launch_bounds__(256) void gemm1_mfma_kernel(const float* __restrict__ x,
                                                         const unsigned short* __restrict__ wt,
                                                         unsigned short* __restrict__ g1, int M) {
    const int t = threadIdx.x;
    const int w = t >> 6, l = t & 63;
    const int lr = l & 15, g = l >> 4;
    const int row = blockIdx.x * 64 + w * 16 + lr;
    const bool rok = row < M;
    float4v acc[4] = {};
    const float* xp = x + (size_t)row * 512 + g * 8;
    const unsigned short* wp = wt + (size_t)lr * 512 + g * 8;
    #pragma unroll 2
    for (int k0 = 0; k0 < 512; k0 += 32) {
        short8v av;
        if (rok) {
            float4 xa = *(const float4*)(xp + k0);
            float4 xb = *(const float4*)(xp + k0 + 4);
            av[0] = (short)bf16rne(xa.x); av[1] = (short)bf16rne(xa.y);
            av[2] = (short)bf16rne(xa.z); av[3] = (short)bf16rne(xa.w);
            av[4] = (short)bf16rne(xb.x); av[5] = (short)bf16rne(xb.y);
            av[6] = (short)bf16rne(xb.z); av[7] = (short)bf16rne(xb.w);
        } else {
            av = short8v{0, 0, 0, 0, 0, 0, 0, 0};
        }
        bf16x8 a = __builtin_bit_cast(bf16x8, av);
        #pragma unroll
        for (int f = 0; f < 4; ++f) {
            bf16x8 b = *(const bf16x8*)(wp + (size_t)f * 16 * 512 + k0);
            acc[f] = __builtin_amdgcn_mfma_f32_16x16x32_bf16(a, b, acc[f], 0, 0, 0);
        }
    }
    const int ro0 = blockIdx.x * 64 + w * 16 + 4 * g;
    #pragma unroll
    for (int f = 0; f < 4; ++f)
        #pragma unroll
        for (int r = 0; r < 4; ++r) {
            int ro = ro0 + r;
            if (ro < M) g1[(size_t)ro * 64 + f * 16 + lr] = bf16rne(acc[f][r]);
        }
}

// ---------------- fused gather + MLP ----------------
// agg = sum_edges dis[s]*dis[n]*gin[s] + dis[n]^2*gin[n]; h = act(agg + bin);
// o = h @ W (+bout if FINAL). LPN lanes/node; edges shared via shfl.
template <int F, int FOUT, int LPN, bool RELU, bool FINAL, bool BF16IN, bool BF16OUT>
__global__ __launch_bounds__(256) void gather_mlp_kernel(
        const int* __restrict__ row_start, const int* __restrict__ csr_src,
        const float* __restrict__ dis, const void* __restrict__ gin_,
        const float* __restrict__ bin, const float* __restrict__ W,
        const float* __restrict__ bout, void* __restrict__ o_, int M) {
    constexpr int VEC = F / LPN;
    constexpr int NPB = 256 / LPN;
    __shared__ float Ws[F * FOUT];
    __shared__ float hs[NPB][F + 4];
    __shared__ float bs[FINAL ? FOUT : 1];
    const int t = threadIdx.x;
    for (int i = t; i < F * FOUT; i += 256) Ws[i] = W[i];
    if (FINAL && t < FOUT) bs[t] = bout[t];
    const int grp = t / LPN, gl = t % LPN;
    const int n = blockIdx.x * NPB + grp;
    if (n < M) {
        const int rs = row_start[n], re = row_start[n + 1];
        const float dn = dis[n];
        float acc[VEC] = {};
        int i = rs;
        while (i < re) {
            int take = re - i;
            int s = 0; float wgt = 0.f;
            if (gl < take) {
                s = csr_src[i + gl];
                wgt = dis[s] * dn;
            }
            #pragma unroll
            for (int jj = 0; jj < LPN; ++jj) {  // zero-w padded
                int sj = __shfl(s, jj, LPN);
                float wj = __shfl(wgt, jj, LPN);
                if (BF16IN) {
                    ushort8v r8 = *(const ushort8v*)((const unsigned short*)gin_ +
                                                     (size_t)sj * F + gl * VEC);
                    #pragma unroll
                    for (int k = 0; k < VEC; ++k) acc[k] += wj * bf16tof(r8[k]);
                } else {
                    float4 v = *(const float4*)((const float*)gin_ +
                                                (size_t)sj * F + gl * VEC);
                    acc[0] += wj * v.x; acc[1] += wj * v.y;
                    acc[2] += wj * v.z; acc[3] += wj * v.w;
                }
            }
            i += LPN;
        }
        // self-loop + bias (+relu)
        const float w2 = dn * dn;
        if (BF16IN) {
            ushort8v r8 = *(const ushort8v*)((const unsigned short*)gin_ +
                                             (size_t)n * F + gl * VEC);
            #pragma unroll
            for (int k = 0; k < VEC; ++k) acc[k] += w2 * bf16tof(r8[k]);
        } else {
            float4 v = *(const float4*)((const float*)gin_ + (size_t)n * F + gl * VEC);
            acc[0] += w2 * v.x; acc[1] += w2 * v.y;
            acc[2] += w2 * v.z; acc[3] += w2 * v.w;
        }
        #pragma unroll
        for (int k = 0; k < VEC; ++k) {
            float r = acc[k] + bin[gl * VEC + k];
            if (RELU) r = fmaxf(r, 0.f);
            hs[grp][gl * VEC + k] = r;
        }
    }
    __syncthreads();
    if (!FINAL) {
        constexpr int OCPT = FOUT / LPN;
        if (n < M) {
            const int oc0 = gl * OCPT;
            float a[OCPT] = {};
            #pragma unroll
            for (int k = 0; k < F; ++k) {
                float hv = hs[grp][k];
                float4 wv = *(const float4*)&Ws[k * FOUT + oc0];  // OCPT==4 always here
                a[0] += hv * wv.x; a[1] += hv * wv.y;
                a[2] += hv * wv.z; a[3] += hv * wv.w;
            }
            if (BF16OUT) {
                ushort4v pk;
                #pragma unroll
                for (int j = 0; j < OCPT; ++j) pk[j] = bf16rne(a[j]);
                *(ushort4v*)((unsigned short*)o_ + (size_t)n * FOUT + oc0) = pk;
            } else {
                float4 v = make_float4(a[0], a[1], a[2], a[3]);
                *(float4*)((float*)o_ + (size_t)n * FOUT + oc0) = v;
            }
        }
    } else {
        float* o = (float*)o_;
        for (int idx = t; idx < NPB * FOUT; idx += 256) {
            int nl = idx / FOUT, oc = idx % FOUT;
            int nn = blockIdx.x * NPB + nl;
            if (nn >= M) continue;
            float a = bs[oc];
            #pragma unroll
            for (int k = 0; k < F; ++k) a += hs[nl][k] * Ws[k * FOUT + oc];
            o[(size_t)nn * FOUT + oc] = a;
        }
    }
}

extern "C" void kernel_launch(void* const* d_in, const int* in_sizes, int n_in,
                              void* d_out, int out_size, void* d_ws, size_t ws_size,
                              hipStream_t stream) {
    const float* x  = (const float*)d_in[0];
    const int* eidx = (const int*)d_in[1];
    const float* W1 = (const float*)d_in[2];
    const float* b1 = (const float*)d_in[3];
    const float* W2 = (const float*)d_in[4];
    const float* b2 = (const float*)d_in[5];
    const float* W3 = (const float*)d_in[6];
    const float* b3 = (const float*)d_in[7];
    const float* Wl = (const float*)d_in[8];
    const float* bl = (const float*)d_in[9];
    float* out = (float*)d_out;

    const int M = in_sizes[0] / 512;
    const int E = in_sizes[1] / 2;
    const int* src = eidx;
    const int* dst = eidx + E;
    const int NB = ceil_div_i(M, 512);
    const int EB = ceil_div_i(E, 4096);

    // workspace (~33 MB)
    char* ws = (char*)d_ws;
    const size_t szM1 = ((size_t)(M + 1) * 4 + 255) & ~(size_t)255;
    const size_t szE  = ((size_t)E * 4 + 255) & ~(size_t)255;
    size_t off = 0;
    int*      bucket_cnt = (int*)(ws + off); off += 2048;
    int*      bb         = (int*)(ws + off); off += 2048;
    int*      gcur       = (int*)(ws + off); off += 2048;
    int*      row_start  = (int*)(ws + off); off += szM1;
    float*    dis        = (float*)(ws + off); off += szM1;
    unsigned* abuf       = (unsigned*)(ws + off); off += szE;
    int*      csr_src    = (int*)(ws + off); off += szE;
    unsigned short* wt   = (unsigned short*)(ws + off); off += 66560;
    unsigned short* g1   = (unsigned short*)(ws + off);
    off += ((size_t)M * 64 * 2 + 255) & ~(size_t)255;
    unsigned short* g2   = (unsigned short*)(ws + off);
    off += ((size_t)M * 32 * 2 + 255) & ~(size_t)255;
    float* g3 = (float*)(ws + off); off += (size_t)M * 16 * 4;

    // CSR build: 4 dispatches + 1KB memset
    hipMemsetAsync(bucket_cnt, 0, 1024, stream);
    bhist_w1t_kernel<<<EB + 128, 256, 0, stream>>>(dst, E, bucket_cnt, EB, W1, wt);
    bscan_kernel<<<1, 256, 0, stream>>>(bucket_cnt, bb, gcur, row_start, NB, M, E);
    bucket_scatter_kernel<<<EB, 256, 0, stream>>>(src, dst, gcur, abuf, E);
    build_kernel<<<NB, 256, 0, stream>>>(bb, abuf, row_start, dis, csr_src, M);

    // layer 1 GEMM (MFMA, bf16 out)
    gemm1_mfma_kernel<<<ceil_div_i(M, 64), 256, 0, stream>>>(x, wt, g1, M);

    // fused gather+MLP layers
    gather_mlp_kernel<64, 32, 8, true, false, true, true>
        <<<ceil_div_i(M, 32), 256, 0, stream>>>(
        row_start, csr_src, dis, g1, b1, W2, nullptr, g2, M);
    gather_mlp_kernel<32, 16, 4, true, false, true, false>
        <<<ceil_div_i(M, 64), 256, 0, stream>>>(
        row_start, csr_src, dis, g2, b2, W3, nullptr, g3, M);
    gather_mlp_kernel<16, 7, 4, false, true, false, false>
        <<<ceil_div_i(M, 64), 256, 0, stream>>>(
        row_start, csr_src, dis, g3, b3, Wl, bl, out, M);
}

// Round 7
// 245.350 us; speedup vs baseline: 10.5668x; 1.0054x over previous
//
#include <hip/hip_runtime.h>

// GCN 3-layer on MI355X. R7:
//  - CSR: bhist(+w1t) -> bscan -> bucket_scatter -> rowdis -> place(ew int2).
//    Edge list = (src, w_f32) pairs: gathers have NO dependent dis[s] chain.
//  - Gathers: 2 edges/lane/batch (2x int2 loads) for ILP; LPN-lane groups
//    share edges via shfl; g1,g2 bf16; fused per-node MLP after aggregation.

typedef __bf16 bf16x8 __attribute__((ext_vector_type(8)));
typedef short short8v __attribute__((ext_vector_type(8)));
typedef unsigned short ushort8v __attribute__((ext_vector_type(8)));
typedef unsigned short ushort4v __attribute__((ext_vector_type(4)));
typedef float float4v __attribute__((ext_vector_type(4)));

static inline int ceil_div_i(long long a, long long b) { return (int)((a + b - 1) / b); }

__device__ inline unsigned short bf16rne(float f) {
    union { float f; unsigned u; } c; c.f = f;
    unsigned u = c.u;
    u += 0x7fffu + ((u >> 16) & 1u);
    return (unsigned short)(u >> 16);
}
__device__ inline float bf16tof(unsigned short h) {
    return __uint_as_float((unsigned)h << 16);
}

// ---------------- pass 1: bucket histogram (dst>>9) + W1 transpose ----------------
__global__ __launch_bounds__(256) void bhist_w1t_kernel(const int* __restrict__ dst, int E,
                                                        int* __restrict__ bucket_cnt, int EB,
                                                        const float* __restrict__ W1,
                                                        unsigned short* __restrict__ wt) {
    const int t = threadIdx.x;
    if (blockIdx.x >= EB) {  // w1t part: 128 blocks
        int i = (blockIdx.x - EB) * 256 + t;
        if (i < 512 * 64) {
            int k = i >> 6, n = i & 63;
            wt[(size_t)n * 512 + k] = bf16rne(W1[i]);
        }
        return;
    }
    __shared__ int h[256];
    h[t] = 0;
    __syncthreads();
    const int e0 = blockIdx.x * 4096;
    const int e1 = min(e0 + 4096, E);
    for (int e = e0 + t; e < e1; e += 256) atomicAdd(&h[dst[e] >> 9], 1);
    __syncthreads();
    if (h[t]) atomicAdd(&bucket_cnt[t], h[t]);
}

// ---------------- pass 2: scan bucket counts -> bases + cursors ----------------
__global__ __launch_bounds__(256) void bscan_kernel(const int* __restrict__ bucket_cnt,
                                                    int* __restrict__ bb,
                                                    int* __restrict__ gcur,
                                                    int* __restrict__ row_start,
                                                    int NB, int M, int E) {
    __shared__ int wsum_[4];
    const int t = threadIdx.x, lane = t & 63, wid = t >> 6;
    int v = (t < NB) ? bucket_cnt[t] : 0;
    int inc = v;
    #pragma unroll
    for (int d = 1; d < 64; d <<= 1) {
        int o = __shfl_up(inc, d);
        if (lane >= d) inc += o;
    }
    if (lane == 63) wsum_[wid] = inc;
    __syncthreads();
    int wpre = 0;
    for (int ww = 0; ww < wid; ++ww) wpre += wsum_[ww];
    int excl = wpre + inc - v;
    if (t < NB) { bb[t] = excl; gcur[t] = excl; }
    if (t == 0) { bb[NB] = E; row_start[M] = E; }
}

// ---------------- pass 3: scatter edges into dst-buckets ----------------
// abuf[pos] = (dst&511)<<23 | src   (needs M < 2^23)
__global__ __launch_bounds__(256) void bucket_scatter_kernel(const int* __restrict__ src,
                                                             const int* __restrict__ dst,
                                                             int* __restrict__ gcur,
                                                             unsigned* __restrict__ abuf, int E) {
    __shared__ int cur[256];
    const int t = threadIdx.x;
    const int e0 = blockIdx.x * 4096;
    const int e1 = min(e0 + 4096, E);
    cur[t] = 0;
    __syncthreads();
    for (int e = e0 + t; e < e1; e += 256) atomicAdd(&cur[dst[e] >> 9], 1);
    __syncthreads();
    int c = cur[t];
    cur[t] = c ? atomicAdd(&gcur[t], c) : 0;
    __syncthreads();
    for (int e = e0 + t; e < e1; e += 256) {
        int d = dst[e];
        int pos = atomicAdd(&cur[d >> 9], 1);
        abuf[pos] = ((unsigned)(d & 511) << 23) | (unsigned)src[e];
    }
}

// ---------------- pass 4: per-bucket hist + scan -> row_start, dis ----------------
__global__ __launch_bounds__(256) void rowdis_kernel(const int* __restrict__ bb,
                                                     const unsigned* __restrict__ abuf,
                                                     int* __restrict__ row_start,
                                                     float* __restrict__ dis, int M) {
    __shared__ int hist[512];
    __shared__ int wsum_[4];
    const int b = blockIdx.x, t = threadIdx.x, lane = t & 63, wid = t >> 6;
    const int n0 = b << 9;
    hist[t] = 0; hist[t + 256] = 0;
    __syncthreads();
    const int s = bb[b], e = bb[b + 1];
    for (int i = s + t; i < e; i += 256) atomicAdd(&hist[abuf[i] >> 23], 1);
    __syncthreads();
    int c0 = hist[2 * t], c1 = hist[2 * t + 1];
    int pair = c0 + c1;
    int inc = pair;
    #pragma unroll
    for (int d = 1; d < 64; d <<= 1) {
        int o = __shfl_up(inc, d);
        if (lane >= d) inc += o;
    }
    if (lane == 63) wsum_[wid] = inc;
    __syncthreads();
    int wpre = 0;
    for (int ww = 0; ww < wid; ++ww) wpre += wsum_[ww];
    int excl = wpre + inc - pair;  // exclusive over pairs
    int r0 = s + excl, r1 = r0 + c0;
    int n = n0 + 2 * t;
    if (n < M)     { row_start[n] = r0;     dis[n] = rsqrtf((float)(c0 + 1)); }
    if (n + 1 < M) { row_start[n + 1] = r1; dis[n + 1] = rsqrtf((float)(c1 + 1)); }
}

// ---------------- pass 5: place edges with precomputed weight ----------------
__global__ __launch_bounds__(256) void place_kernel(const int* __restrict__ bb,
                                                    const unsigned* __restrict__ abuf,
                                                    const int* __restrict__ row_start,
                                                    const float* __restrict__ dis,
                                                    int2* __restrict__ ew, int M) {
    __shared__ int cur[512];
    __shared__ float disl[512];
    const int b = blockIdx.x, t = threadIdx.x;
    const int n0 = b << 9;
    for (int i = t; i < 512; i += 256) {
        int n = n0 + i;
        cur[i] = (n < M) ? row_start[n] : 0;
        disl[i] = (n < M) ? dis[n] : 0.f;
    }
    __syncthreads();
    const int s = bb[b], e = bb[b + 1];
    for (int i = s + t; i < e; i += 256) {
        unsigned p = abuf[i];
        int ld = p >> 23;
        int sr = (int)(p & 0x7fffffu);
        float w = dis[sr] * disl[ld];
        int pos = atomicAdd(&cur[ld], 1);
        ew[pos] = make_int2(sr, __float_as_int(w));
    }
}

// ---------------- GEMM1 via MFMA: g1(bf16) = x @ W1, [M,512]@[512,64] ----------------
__global__ __launch_bounds__(256) void gemm1_mfma_kernel(const float* __restrict__ x,
                                                         const unsigned short* __restrict__ wt,
                                                         unsigned short* __restrict__ g1, int M) {
    const int t = threadIdx.x;
    const int w = t >> 6, l = t & 63;
    const int lr = l & 15, g = l >> 4;
    const int row = blockIdx.x * 64 + w * 16 + lr;
    const bool rok = row < M;
    float4v acc[4] = {};
    const float* xp = x + (size_t)row * 512 + g * 8;
    const unsigned short* wp = wt + (size_t)lr * 512 + g * 8;
    #pragma unroll 2
    for (int k0 = 0; k0 < 512; k0 += 32) {
        short8v av;
        if (rok) {
            float4 xa = *(const float4*)(xp + k0);
            float4 xb = *(const float4*)(xp + k0 + 4);
            av[0] = (short)bf16rne(xa.x); av[1] = (short)bf16rne(xa.y);
            av[2] = (short)bf16rne(xa.z); av[3] = (short)bf16rne(xa.w);
            av[4] = (short)bf16rne(xb.x); av[5] = (short)bf16rne(xb.y);
            av[6] = (short)bf16rne(xb.z); av[7] = (short)bf16rne(xb.w);
        } else {
            av = short8v{0, 0, 0, 0, 0, 0, 0, 0};
        }
        bf16x8 a = __builtin_bit_cast(bf16x8, av);
        #pragma unroll
        for (int f = 0; f < 4; ++f) {
            bf16x8 b = *(const bf16x8*)(wp + (size_t)f * 16 * 512 + k0);
            acc[f] = __builtin_amdgcn_mfma_f32_16x16x32_bf16(a, b, acc[f], 0, 0, 0);
        }
    }
    const int ro0 = blockIdx.x * 64 + w * 16 + 4 * g;
    #pragma unroll
    for (int f = 0; f < 4; ++f)
        #pragma unroll
        for (int r = 0; r < 4; ++r) {
            int ro = ro0 + r;
            if (ro < M) g1[(size_t)ro * 64 + f * 16 + lr] = bf16rne(acc[f][r]);
        }
}

// ---------------- fused gather + MLP ----------------
// agg = sum_edges w_e * gin[s] + dis[n]^2 * gin[n]; h = act(agg + bin);
// o = h @ W (+bout if FINAL). LPN lanes/node; 2 edges/lane/batch via shfl.
template <int F, int FOUT, int LPN, bool RELU, bool FINAL, bool BF16IN, bool BF16OUT>
__global__ __launch_bounds__(256) void gather_mlp_kernel(
        const int* __restrict__ row_start, const int2* __restrict__ ew,
        const float* __restrict__ dis, const void* __restrict__ gin_,
        const float* __restrict__ bin, const float* __restrict__ W,
        const float* __restrict__ bout, void* __restrict__ o_, int M) {
    constexpr int VEC = F / LPN;
    constexpr int NPB = 256 / LPN;
    __shared__ float Ws[F * FOUT];
    __shared__ float hs[NPB][F + 4];
    __shared__ float bs[FINAL ? FOUT : 1];
    const int t = threadIdx.x;
    for (int i = t; i < F * FOUT; i += 256) Ws[i] = W[i];
    if (FINAL && t < FOUT) bs[t] = bout[t];
    const int grp = t / LPN, gl = t % LPN;
    const int n = blockIdx.x * NPB + grp;
    if (n < M) {
        const int rs = row_start[n], re = row_start[n + 1];
        const float dn = dis[n];
        float acc[VEC] = {};
        int i = rs;
        while (i < re) {
            // 2 edges per lane: ew[i + 2*gl], ew[i + 2*gl + 1] (zero-w padded)
            int s0 = 0, s1 = 0; float w0 = 0.f, w1 = 0.f;
            const int base = i + 2 * gl;
            if (base < re) {
                int2 p0 = ew[base];
                s0 = p0.x; w0 = __int_as_float(p0.y);
                if (base + 1 < re) {
                    int2 p1 = ew[base + 1];
                    s1 = p1.x; w1 = __int_as_float(p1.y);
                }
            }
            #pragma unroll
            for (int jj = 0; jj < 2 * LPN; ++jj) {
                int sj = __shfl((jj & 1) ? s1 : s0, jj >> 1, LPN);
                float wj = __shfl((jj & 1) ? w1 : w0, jj >> 1, LPN);
                if (BF16IN) {
                    ushort8v r8 = *(const ushort8v*)((const unsigned short*)gin_ +
                                                     (size_t)sj * F + gl * VEC);
                    #pragma unroll
                    for (int k = 0; k < VEC; ++k) acc[k] += wj * bf16tof(r8[k]);
                } else {
                    float4 v = *(const float4*)((const float*)gin_ +
                                                (size_t)sj * F + gl * VEC);
                    acc[0] += wj * v.x; acc[1] += wj * v.y;
                    acc[2] += wj * v.z; acc[3] += wj * v.w;
                }
            }
            i += 2 * LPN;
        }
        // self-loop + bias (+relu)
        const float w2 = dn * dn;
        if (BF16IN) {
            ushort8v r8 = *(const ushort8v*)((const unsigned short*)gin_ +
                                             (size_t)n * F + gl * VEC);
            #pragma unroll
            for (int k = 0; k < VEC; ++k) acc[k] += w2 * bf16tof(r8[k]);
        } else {
            float4 v = *(const float4*)((const float*)gin_ + (size_t)n * F + gl * VEC);
            acc[0] += w2 * v.x; acc[1] += w2 * v.y;
            acc[2] += w2 * v.z; acc[3] += w2 * v.w;
        }
        #pragma unroll
        for (int k = 0; k < VEC; ++k) {
            float r = acc[k] + bin[gl * VEC + k];
            if (RELU) r = fmaxf(r, 0.f);
            hs[grp][gl * VEC + k] = r;
        }
    }
    __syncthreads();
    if (!FINAL) {
        constexpr int OCPT = FOUT / LPN;  // 4 in both non-final layers
        if (n < M) {
            const int oc0 = gl * OCPT;
            float a[OCPT] = {};
            #pragma unroll
            for (int k = 0; k < F; ++k) {
                float hv = hs[grp][k];
                float4 wv = *(const float4*)&Ws[k * FOUT + oc0];
                a[0] += hv * wv.x; a[1] += hv * wv.y;
                a[2] += hv * wv.z; a[3] += hv * wv.w;
            }
            if (BF16OUT) {
                ushort4v pk;
                #pragma unroll
                for (int j = 0; j < OCPT; ++j) pk[j] = bf16rne(a[j]);
                *(ushort4v*)((unsigned short*)o_ + (size_t)n * FOUT + oc0) = pk;
            } else {
                float4 v = make_float4(a[0], a[1], a[2], a[3]);
                *(float4*)((float*)o_ + (size_t)n * FOUT + oc0) = v;
            }
        }
    } else {
        float* o = (float*)o_;
        for (int idx = t; idx < NPB * FOUT; idx += 256) {
            int nl = idx / FOUT, oc = idx % FOUT;
            int nn = blockIdx.x * NPB + nl;
            if (nn >= M) continue;
            float a = bs[oc];
            #pragma unroll
            for (int k = 0; k < F; ++k) a += hs[nl][k] * Ws[k * FOUT + oc];
            o[(size_t)nn * FOUT + oc] = a;
        }
    }
}

extern "C" void kernel_launch(void* const* d_in, const int* in_sizes, int n_in,
                              void* d_out, int out_size, void* d_ws, size_t ws_size,
                              hipStream_t stream) {
    const float* x  = (const float*)d_in[0];
    const int* eidx = (const int*)d_in[1];
    const float* W1 = (const float*)d_in[2];
    const float* b1 = (const float*)d_in[3];
    const float* W2 = (const float*)d_in[4];
    const float* b2 = (const float*)d_in[5];
    const float* W3 = (const float*)d_in[6];
    const float* b3 = (const float*)d_in[7];
    const float* Wl = (const float*)d_in[8];
    const float* bl = (const float*)d_in[9];
    float* out = (float*)d_out;

    const int M = in_sizes[0] / 512;
    const int E = in_sizes[1] / 2;
    const int* src = eidx;
    const int* dst = eidx + E;
    const int NB = ceil_div_i(M, 512);
    const int EB = ceil_div_i(E, 4096);

    // workspace (~46 MB)
    char* ws = (char*)d_ws;
    const size_t szM1 = ((size_t)(M + 1) * 4 + 255) & ~(size_t)255;
    const size_t szE  = ((size_t)E * 4 + 255) & ~(size_t)255;
    size_t off = 0;
    int*      bucket_cnt = (int*)(ws + off); off += 2048;
    int*      bb         = (int*)(ws + off); off += 2048;
    int*      gcur       = (int*)(ws + off); off += 2048;
    int*      row_start  = (int*)(ws + off); off += szM1;
    float*    dis        = (float*)(ws + off); off += szM1;
    unsigned* abuf       = (unsigned*)(ws + off); off += szE;
    int2*     ew         = (int2*)(ws + off); off += 2 * szE;
    unsigned short* wt   = (unsigned short*)(ws + off); off += 66560;
    unsigned short* g1   = (unsigned short*)(ws + off);
    off += ((size_t)M * 64 * 2 + 255) & ~(size_t)255;
    unsigned short* g2   = (unsigned short*)(ws + off);
    off += ((size_t)M * 32 * 2 + 255) & ~(size_t)255;
    float* g3 = (float*)(ws + off); off += (size_t)M * 16 * 4;

    // CSR build
    hipMemsetAsync(bucket_cnt, 0, 1024, stream);
    bhist_w1t_kernel<<<EB + 128, 256, 0, stream>>>(dst, E, bucket_cnt, EB, W1, wt);
    bscan_kernel<<<1, 256, 0, stream>>>(bucket_cnt, bb, gcur, row_start, NB, M, E);
    bucket_scatter_kernel<<<EB, 256, 0, stream>>>(src, dst, gcur, abuf, E);
    rowdis_kernel<<<NB, 256, 0, stream>>>(bb, abuf, row_start, dis, M);
    place_kernel<<<NB, 256, 0, stream>>>(bb, abuf, row_start, dis, ew, M);

    // layer 1 GEMM (MFMA, bf16 out)
    gemm1_mfma_kernel<<<ceil_div_i(M, 64), 256, 0, stream>>>(x, wt, g1, M);

    // fused gather+MLP layers
    gather_mlp_kernel<64, 32, 8, true, false, true, true>
        <<<ceil_div_i(M, 32), 256, 0, stream>>>(
        row_start, ew, dis, g1, b1, W2, nullptr, g2, M);
    gather_mlp_kernel<32, 16, 4, true, false, true, false>
        <<<ceil_div_i(M, 64), 256, 0, stream>>>(
        row_start, ew, dis, g2, b2, W3, nullptr, g3, M);
    gather_mlp_kernel<16, 7, 4, false, true, false, false>
        <<<ceil_div_i(M, 64), 256, 0, stream>>>(
        row_start, ew, dis, g3, b3, Wl, bl, out, M);
}

// Round 9
// 229.964 us; speedup vs baseline: 11.2738x; 1.0669x over previous
//
#include <hip/hip_runtime.h>

// GCN 3-layer on MI355X. R9: pre-scaled features g'[v] = dis[v]*g[v] make the
// aggregation weight-free: agg = dis[n]*(sum g'[src] + g'[n]). No ew array,
// no place pass, no per-edge dis chain. CSR via single-pass fixed-capacity
// bucket arena (no hist/scan prepass). 7 dispatches:
//   init(W1^T + arena tails) -> arena scatter -> build(row_start/end+dis+csr)
//   -> gemm1 MFMA (dis-scaled bf16 out) -> gather1 -> gather2 -> gather3.

typedef __bf16 bf16x8 __attribute__((ext_vector_type(8)));
typedef short short8v __attribute__((ext_vector_type(8)));
typedef unsigned short ushort8v __attribute__((ext_vector_type(8)));
typedef unsigned short ushort4v __attribute__((ext_vector_type(4)));
typedef float float4v __attribute__((ext_vector_type(4)));

static inline int ceil_div_i(long long a, long long b) { return (int)((a + b - 1) / b); }

#define CAP 16384  // per-bucket arena capacity (mean ~8.2k for E=1.6M, NB=196)

__device__ inline unsigned short bf16rne(float f) {
    union { float f; unsigned u; } c; c.f = f;
    unsigned u = c.u;
    u += 0x7fffu + ((u >> 16) & 1u);
    return (unsigned short)(u >> 16);
}
__device__ inline float bf16tof(unsigned short h) {
    return __uint_as_float((unsigned)h << 16);
}

// ---------------- D1: arena tails + W1 -> bf16 transposed [64][512] ----------------
__global__ __launch_bounds__(256) void init_kernel(const float* __restrict__ W1,
                                                   unsigned short* __restrict__ wt,
                                                   int* __restrict__ gtail) {
    const int t = threadIdx.x;
    if (blockIdx.x == 0) gtail[t] = t * CAP;
    for (int i = blockIdx.x * 256 + t; i < 512 * 64; i += gridDim.x * 256) {
        int k = i >> 6, n = i & 63;
        wt[(size_t)n * 512 + k] = bf16rne(W1[i]);
    }
}

// ---------------- D2: single-pass scatter into per-bucket arena ----------------
// abuf[pos] = (dst&511)<<23 | src   (M < 2^23)
__global__ __launch_bounds__(256) void scatter_kernel(const int* __restrict__ src,
                                                      const int* __restrict__ dst,
                                                      int* __restrict__ gtail,
                                                      unsigned* __restrict__ abuf, int E) {
    __shared__ int cur[256];
    const int t = threadIdx.x;
    const int e0 = blockIdx.x * 4096;
    const int e1 = min(e0 + 4096, E);
    cur[t] = 0;
    __syncthreads();
    for (int e = e0 + t; e < e1; e += 256) atomicAdd(&cur[dst[e] >> 9], 1);
    __syncthreads();
    int c = cur[t];
    cur[t] = c ? atomicAdd(&gtail[t], c) : 0;  // block's run base in bucket arena
    __syncthreads();
    for (int e = e0 + t; e < e1; e += 256) {
        int d = dst[e];
        int pos = atomicAdd(&cur[d >> 9], 1);
        abuf[pos] = ((unsigned)(d & 511) << 23) | (unsigned)src[e];
    }
}

// ---------------- D3: per-bucket hist+scan -> row_start/row_end/dis, place csr ----------------
__global__ __launch_bounds__(256) void build_kernel(const int* __restrict__ gtail,
                                                    const unsigned* __restrict__ abuf,
                                                    int* __restrict__ row_start,
                                                    int* __restrict__ row_end,
                                                    float* __restrict__ dis,
                                                    int* __restrict__ csr_src, int M) {
    __shared__ int hist[512];
    __shared__ int cur[512];
    __shared__ int wsum_[4];
    const int b = blockIdx.x, t = threadIdx.x, lane = t & 63, wid = t >> 6;
    const int n0 = b << 9;
    const int s = b * CAP;
    const int e = gtail[b];  // s + count (final tail after scatter)
    hist[t] = 0; hist[t + 256] = 0;
    __syncthreads();
    for (int i = s + t; i < e; i += 256) atomicAdd(&hist[abuf[i] >> 23], 1);
    __syncthreads();
    int c0 = hist[2 * t], c1 = hist[2 * t + 1];
    int pair = c0 + c1;
    int inc = pair;
    #pragma unroll
    for (int d = 1; d < 64; d <<= 1) {
        int o = __shfl_up(inc, d);
        if (lane >= d) inc += o;
    }
    if (lane == 63) wsum_[wid] = inc;
    __syncthreads();
    int wpre = 0;
    for (int ww = 0; ww < wid; ++ww) wpre += wsum_[ww];
    int excl = wpre + inc - pair;  // exclusive over node pairs
    int r0 = s + excl, r1 = r0 + c0;
    int n = n0 + 2 * t;
    if (n < M) {
        row_start[n] = r0; row_end[n] = r1;
        dis[n] = rsqrtf((float)(c0 + 1));
    }
    if (n + 1 < M) {
        row_start[n + 1] = r1; row_end[n + 1] = r1 + c1;
        dis[n + 1] = rsqrtf((float)(c1 + 1));
    }
    cur[2 * t] = r0; cur[2 * t + 1] = r1;
    __syncthreads();
    for (int i = s + t; i < e; i += 256) {
        unsigned p = abuf[i];
        int pos = atomicAdd(&cur[p >> 23], 1);
        csr_src[pos] = (int)(p & 0x7fffffu);
    }
}

// ---------------- D4: GEMM1 MFMA, g1'(bf16) = dis[row] * (x @ W1) ----------------
__global__ __launch_bounds__(256) void gemm1_mfma_kernel(const float* __restrict__ x,
                                                         const unsigned short* __restrict__ wt,
                                                         const float* __restrict__ dis,
                                                         unsigned short* __restrict__ g1, int M) {
    const int t = threadIdx.x;
    const int w = t >> 6, l = t & 63;
    const int lr = l & 15, g = l >> 4;
    const int row = blockIdx.x * 64 + w * 16 + lr;
    const bool rok = row < M;
    float4v acc[4] = {};
    const float* xp = x + (size_t)row * 512 + g * 8;
    const unsigned short* wp = wt + (size_t)lr * 512 + g * 8;
    #pragma unroll 2
    for (int k0 = 0; k0 < 512; k0 += 32) {
        short8v av;
        if (rok) {
            float4 xa = *(const float4*)(xp + k0);
            float4 xb = *(const float4*)(xp + k0 + 4);
            av[0] = (short)bf16rne(xa.x); av[1] = (short)bf16rne(xa.y);
            av[2] = (short)bf16rne(xa.z); av[3] = (short)bf16rne(xa.w);
            av[4] = (short)bf16rne(xb.x); av[5] = (short)bf16rne(xb.y);
            av[6] = (short)bf16rne(xb.z); av[7] = (short)bf16rne(xb.w);
        } else {
            av = short8v{0, 0, 0, 0, 0, 0, 0, 0};
        }
        bf16x8 a = __builtin_bit_cast(bf16x8, av);
        #pragma unroll
        for (int f = 0; f < 4; ++f) {
            bf16x8 b = *(const bf16x8*)(wp + (size_t)f * 16 * 512 + k0);
            acc[f] = __builtin_amdgcn_mfma_f32_16x16x32_bf16(a, b, acc[f], 0, 0, 0);
        }
    }
    const int ro0 = blockIdx.x * 64 + w * 16 + 4 * g;
    #pragma unroll
    for (int r = 0; r < 4; ++r) {
        int ro = ro0 + r;
        if (ro < M) {
            float dsc = dis[ro];  // same addr across the 16 lr lanes -> broadcast
            #pragma unroll
            for (int f = 0; f < 4; ++f)
                g1[(size_t)ro * 64 + f * 16 + lr] = bf16rne(acc[f][r] * dsc);
        }
    }
}

// ---------------- D5-D7: weight-free gather + fused MLP ----------------
// pre = sum_edges gin[s] + gin[n]   (gin rows are pre-scaled by dis[src])
// h = act(dis[n]*pre + bin); non-final: o[n] = bf16( dis[n] * (h @ W) )
// final: o[n] = h @ Wl + bl (f32).
template <int F, int FOUT, int LPN, bool RELU, bool FINAL>
__global__ __launch_bounds__(256) void gather_mlp_kernel(
        const int* __restrict__ row_start, const int* __restrict__ row_end,
        const int* __restrict__ csr_src, const float* __restrict__ dis,
        const unsigned short* __restrict__ gin, const float* __restrict__ bin,
        const float* __restrict__ W, const float* __restrict__ bout,
        void* __restrict__ o_, int M) {
    constexpr int VEC = F / LPN;      // 8 or 4 bf16 per lane
    constexpr int NPB = 256 / LPN;
    constexpr int HSS = F + 4;
    __shared__ float Ws[F * FOUT];
    __shared__ float hs[NPB][HSS];
    __shared__ float bs[FINAL ? FOUT : 1];
    const int t = threadIdx.x;
    for (int i = t; i < F * FOUT; i += 256) Ws[i] = W[i];
    if (FINAL && t < FOUT) bs[t] = bout[t];
    const int grp = t / LPN, gl = t % LPN;
    const int n = blockIdx.x * NPB + grp;
    float dn = 0.f;
    if (n < M) {
        const int rs = row_start[n], re = row_end[n];
        dn = dis[n];
        float acc[VEC] = {};
        int i = rs;
        while (i < re) {
            const int take = re - i;  // uniform within the LPN-lane group
            int s = 0;
            if (gl < take) s = csr_src[i + gl];
            #pragma unroll
            for (int jj = 0; jj < LPN; ++jj) {
                if (jj < take) {
                    int sj = __shfl(s, jj, LPN);
                    if constexpr (VEC == 8) {
                        ushort8v r8 = *(const ushort8v*)(gin + (size_t)sj * F + gl * 8);
                        #pragma unroll
                        for (int k = 0; k < 8; ++k) acc[k] += bf16tof(r8[k]);
                    } else {
                        ushort4v r4 = *(const ushort4v*)(gin + (size_t)sj * F + gl * 4);
                        #pragma unroll
                        for (int k = 0; k < 4; ++k) acc[k] += bf16tof(r4[k]);
                    }
                }
            }
            i += LPN;
        }
        // self-loop: + gin[n] (already dis[n]-scaled)
        if constexpr (VEC == 8) {
            ushort8v r8 = *(const ushort8v*)(gin + (size_t)n * F + gl * 8);
            #pragma unroll
            for (int k = 0; k < 8; ++k) acc[k] += bf16tof(r8[k]);
        } else {
            ushort4v r4 = *(const ushort4v*)(gin + (size_t)n * F + gl * 4);
            #pragma unroll
            for (int k = 0; k < 4; ++k) acc[k] += bf16tof(r4[k]);
        }
        #pragma unroll
        for (int k = 0; k < VEC; ++k) {
            float r = dn * acc[k] + bin[gl * VEC + k];
            if (RELU) r = fmaxf(r, 0.f);
            hs[grp][gl * VEC + k] = r;
        }
    }
    __syncthreads();
    if (!FINAL) {
        constexpr int OCPT = FOUT / LPN;  // 4 (layer1) or 2 (layer2)
        if (n < M) {
            const int oc0 = gl * OCPT;
            float a[OCPT] = {};
            #pragma unroll
            for (int k = 0; k < F; ++k) {
                float hv = hs[grp][k];
                if constexpr (OCPT == 4) {
                    float4 wv = *(const float4*)&Ws[k * FOUT + oc0];
                    a[0] += hv * wv.x; a[1] += hv * wv.y;
                    a[2] += hv * wv.z; a[3] += hv * wv.w;
                } else {
                    float2 wv = *(const float2*)&Ws[k * FOUT + oc0];
                    a[0] += hv * wv.x; a[1] += hv * wv.y;
                }
            }
            unsigned short* o = (unsigned short*)o_;
            if constexpr (OCPT == 4) {
                ushort4v pk;
                #pragma unroll
                for (int j = 0; j < 4; ++j) pk[j] = bf16rne(a[j] * dn);
                *(ushort4v*)(o + (size_t)n * FOUT + oc0) = pk;
            } else {
                #pragma unroll
                for (int j = 0; j < OCPT; ++j)
                    o[(size_t)n * FOUT + oc0 + j] = bf16rne(a[j] * dn);
            }
        }
    } else {
        float* o = (float*)o_;
        for (int idx = t; idx < NPB * FOUT; idx += 256) {
            int nl = idx / FOUT, oc = idx % FOUT;
            int nn = blockIdx.x * NPB + nl;
            if (nn >= M) continue;
            float a = bs[oc];
            #pragma unroll
            for (int k = 0; k < F; ++k) a += hs[nl][k] * Ws[k * FOUT + oc];
            o[(size_t)nn * FOUT + oc] = a;
        }
    }
}

extern "C" void kernel_launch(void* const* d_in, const int* in_sizes, int n_in,
                              void* d_out, int out_size, void* d_ws, size_t ws_size,
                              hipStream_t stream) {
    const float* x  = (const float*)d_in[0];
    const int* eidx = (const int*)d_in[1];
    const float* W1 = (const float*)d_in[2];
    const float* b1 = (const float*)d_in[3];
    const float* W2 = (const float*)d_in[4];
    const float* b2 = (const float*)d_in[5];
    const float* W3 = (const float*)d_in[6];
    const float* b3 = (const float*)d_in[7];
    const float* Wl = (const float*)d_in[8];
    const float* bl = (const float*)d_in[9];
    float* out = (float*)d_out;

    const int M = in_sizes[0] / 512;
    const int E = in_sizes[1] / 2;
    const int* src = eidx;
    const int* dst = eidx + E;
    const int NB = ceil_div_i(M, 512);   // 196 for M=100k (<=256)
    const int EB = ceil_div_i(E, 4096);

    // workspace (~49 MB)
    char* ws = (char*)d_ws;
    const size_t szM1 = ((size_t)(M + 1) * 4 + 255) & ~(size_t)255;
    const size_t szAR = ((size_t)NB * CAP * 4 + 255) & ~(size_t)255;  // 12.85MB
    size_t off = 0;
    int*      gtail     = (int*)(ws + off); off += 1024;
    int*      row_start = (int*)(ws + off); off += szM1;
    int*      row_end   = (int*)(ws + off); off += szM1;
    float*    dis       = (float*)(ws + off); off += szM1;
    unsigned* abuf      = (unsigned*)(ws + off); off += szAR;
    int*      csr_src   = (int*)(ws + off); off += szAR;
    unsigned short* wt  = (unsigned short*)(ws + off); off += 66560;
    unsigned short* g1  = (unsigned short*)(ws + off);
    off += ((size_t)M * 64 * 2 + 255) & ~(size_t)255;
    unsigned short* g2  = (unsigned short*)(ws + off);
    off += ((size_t)M * 32 * 2 + 255) & ~(size_t)255;
    unsigned short* g3  = (unsigned short*)(ws + off);
    off += ((size_t)M * 16 * 2 + 255) & ~(size_t)255;

    // D1..D3: CSR build (arena single-pass)
    init_kernel<<<128, 256, 0, stream>>>(W1, wt, gtail);
    scatter_kernel<<<EB, 256, 0, stream>>>(src, dst, gtail, abuf, E);
    build_kernel<<<NB, 256, 0, stream>>>(gtail, abuf, row_start, row_end, dis, csr_src, M);

    // D4: layer-1 GEMM, pre-scaled bf16 output
    gemm1_mfma_kernel<<<ceil_div_i(M, 64), 256, 0, stream>>>(x, wt, dis, g1, M);

    // D5..D7: weight-free gathers with fused MLP
    gather_mlp_kernel<64, 32, 8, true, false><<<ceil_div_i(M, 32), 256, 0, stream>>>(
        row_start, row_end, csr_src, dis, g1, b1, W2, nullptr, g2, M);
    gather_mlp_kernel<32, 16, 8, true, false><<<ceil_div_i(M, 32), 256, 0, stream>>>(
        row_start, row_end, csr_src, dis, g2, b2, W3, nullptr, g3, M);
    gather_mlp_kernel<16, 7, 4, false, true><<<ceil_div_i(M, 64), 256, 0, stream>>>(
        row_start, row_end, csr_src, dis, g3, b3, Wl, bl, out, M);
}

// Round 10
// 214.390 us; speedup vs baseline: 12.0927x; 1.0726x over previous
//
#include <hip/hip_runtime.h>

// GCN 3-layer on MI355X. R10:
//  - FAT dispatch: bucket-arena scatter (blocks [0,EB)) runs CONCURRENTLY with
//    GEMM1 MFMA (blocks [EB,EB+M/64)) — independent data. Enabled by making
//    g1 UNSCALED (gather1 applies per-edge dis[s]*dis[n]; R6 measured this
//    ~free vs precomputed weights).
//  - g2,g3 stay pre-scaled (weight-free gathers 2,3), scaling fused in the
//    producing epilogue.
//  - Scatter chunk 8192 (longer bucket runs, fewer gtail atomics).
//  - 6 dispatches: init -> [scatter||gemm1] -> build -> g1 -> g2 -> g3.

typedef __bf16 bf16x8 __attribute__((ext_vector_type(8)));
typedef short short8v __attribute__((ext_vector_type(8)));
typedef unsigned short ushort8v __attribute__((ext_vector_type(8)));
typedef unsigned short ushort4v __attribute__((ext_vector_type(4)));
typedef float float4v __attribute__((ext_vector_type(4)));

static inline int ceil_div_i(long long a, long long b) { return (int)((a + b - 1) / b); }

#define CAP 16384      // per-bucket arena capacity (mean ~8.2k, 4sigma ~8.5k)
#define SCHUNK 8192    // edges per scatter block

__device__ inline unsigned short bf16rne(float f) {
    union { float f; unsigned u; } c; c.f = f;
    unsigned u = c.u;
    u += 0x7fffu + ((u >> 16) & 1u);
    return (unsigned short)(u >> 16);
}
__device__ inline float bf16tof(unsigned short h) {
    return __uint_as_float((unsigned)h << 16);
}

// ---------------- D1: arena tails + W1 -> bf16 transposed [64][512] ----------------
__global__ __launch_bounds__(256) void init_kernel(const float* __restrict__ W1,
                                                   unsigned short* __restrict__ wt,
                                                   int* __restrict__ gtail) {
    const int t = threadIdx.x;
    if (blockIdx.x == 0) gtail[t] = t * CAP;
    for (int i = blockIdx.x * 256 + t; i < 512 * 64; i += gridDim.x * 256) {
        int k = i >> 6, n = i & 63;
        wt[(size_t)n * 512 + k] = bf16rne(W1[i]);
    }
}

// ---------------- D2: FAT — arena scatter || GEMM1 MFMA (unscaled bf16 out) ----------------
// blocks [0,EB): scatter edges into per-bucket arena; abuf = (dst&511)<<23|src
// blocks [EB,EB+NT): 64-row MFMA tiles of g1 = bf16(x @ W1)
__global__ __launch_bounds__(256) void scatter_gemm1_kernel(
        const int* __restrict__ src, const int* __restrict__ dst,
        int* __restrict__ gtail, unsigned* __restrict__ abuf, int E, int EB,
        const float* __restrict__ x, const unsigned short* __restrict__ wt,
        unsigned short* __restrict__ g1, int M) {
    __shared__ int cur[256];
    const int t = threadIdx.x;
    if (blockIdx.x < EB) {
        // ---- scatter path ----
        const int e0 = blockIdx.x * SCHUNK;
        const int e1 = min(e0 + SCHUNK, E);
        cur[t] = 0;
        __syncthreads();
        for (int e = e0 + t; e < e1; e += 256) atomicAdd(&cur[dst[e] >> 9], 1);
        __syncthreads();
        int c = cur[t];
        cur[t] = c ? atomicAdd(&gtail[t], c) : 0;  // block's run base in bucket
        __syncthreads();
        for (int e = e0 + t; e < e1; e += 256) {
            int d = dst[e];
            int pos = atomicAdd(&cur[d >> 9], 1);
            abuf[pos] = ((unsigned)(d & 511) << 23) | (unsigned)src[e];
        }
        return;
    }
    // ---- gemm1 path ----
    const int tile = blockIdx.x - EB;
    const int w = t >> 6, l = t & 63;
    const int lr = l & 15, g = l >> 4;
    const int row = tile * 64 + w * 16 + lr;
    const bool rok = row < M;
    float4v acc[4] = {};
    const float* xp = x + (size_t)row * 512 + g * 8;
    const unsigned short* wp = wt + (size_t)lr * 512 + g * 8;
    #pragma unroll 2
    for (int k0 = 0; k0 < 512; k0 += 32) {
        short8v av;
        if (rok) {
            float4 xa = *(const float4*)(xp + k0);
            float4 xb = *(const float4*)(xp + k0 + 4);
            av[0] = (short)bf16rne(xa.x); av[1] = (short)bf16rne(xa.y);
            av[2] = (short)bf16rne(xa.z); av[3] = (short)bf16rne(xa.w);
            av[4] = (short)bf16rne(xb.x); av[5] = (short)bf16rne(xb.y);
            av[6] = (short)bf16rne(xb.z); av[7] = (short)bf16rne(xb.w);
        } else {
            av = short8v{0, 0, 0, 0, 0, 0, 0, 0};
        }
        bf16x8 a = __builtin_bit_cast(bf16x8, av);
        #pragma unroll
        for (int f = 0; f < 4; ++f) {
            bf16x8 b = *(const bf16x8*)(wp + (size_t)f * 16 * 512 + k0);
            acc[f] = __builtin_amdgcn_mfma_f32_16x16x32_bf16(a, b, acc[f], 0, 0, 0);
        }
    }
    const int ro0 = tile * 64 + w * 16 + 4 * g;
    #pragma unroll
    for (int f = 0; f < 4; ++f)
        #pragma unroll
        for (int r = 0; r < 4; ++r) {
            int ro = ro0 + r;
            if (ro < M) g1[(size_t)ro * 64 + f * 16 + lr] = bf16rne(acc[f][r]);
        }
}

// ---------------- D3: per-bucket hist+scan -> row_start/row_end/dis, place csr ----------------
__global__ __launch_bounds__(256) void build_kernel(const int* __restrict__ gtail,
                                                    const unsigned* __restrict__ abuf,
                                                    int* __restrict__ row_start,
                                                    int* __restrict__ row_end,
                                                    float* __restrict__ dis,
                                                    int* __restrict__ csr_src, int M) {
    __shared__ int hist[512];
    __shared__ int cur[512];
    __shared__ int wsum_[4];
    const int b = blockIdx.x, t = threadIdx.x, lane = t & 63, wid = t >> 6;
    const int n0 = b << 9;
    const int s = b * CAP;
    const int e = gtail[b];
    hist[t] = 0; hist[t + 256] = 0;
    __syncthreads();
    for (int i = s + t; i < e; i += 256) atomicAdd(&hist[abuf[i] >> 23], 1);
    __syncthreads();
    int c0 = hist[2 * t], c1 = hist[2 * t + 1];
    int pair = c0 + c1;
    int inc = pair;
    #pragma unroll
    for (int d = 1; d < 64; d <<= 1) {
        int o = __shfl_up(inc, d);
        if (lane >= d) inc += o;
    }
    if (lane == 63) wsum_[wid] = inc;
    __syncthreads();
    int wpre = 0;
    for (int ww = 0; ww < wid; ++ww) wpre += wsum_[ww];
    int excl = wpre + inc - pair;
    int r0 = s + excl, r1 = r0 + c0;
    int n = n0 + 2 * t;
    if (n < M) {
        row_start[n] = r0; row_end[n] = r1;
        dis[n] = rsqrtf((float)(c0 + 1));
    }
    if (n + 1 < M) {
        row_start[n + 1] = r1; row_end[n + 1] = r1 + c1;
        dis[n + 1] = rsqrtf((float)(c1 + 1));
    }
    cur[2 * t] = r0; cur[2 * t + 1] = r1;
    __syncthreads();
    for (int i = s + t; i < e; i += 256) {
        unsigned p = abuf[i];
        int pos = atomicAdd(&cur[p >> 23], 1);
        csr_src[pos] = (int)(p & 0x7fffffu);
    }
}

// ---------------- D4-D6: gather + fused MLP ----------------
// EDGEW (layer1): acc = sum_e dis[s]*dn*gin[s] + dn^2*gin[n]; h = act(acc+bin)
// else (pre-scaled gin): acc = sum_e gin[s] + gin[n];        h = act(dn*acc+bin)
// non-final: o[n] = bf16(dn * (h @ W))  [pre-scaled for next layer]
// final:     o[n] = h @ Wl + bl  (f32)
template <int F, int FOUT, int LPN, bool RELU, bool FINAL, bool EDGEW>
__global__ __launch_bounds__(256) void gather_mlp_kernel(
        const int* __restrict__ row_start, const int* __restrict__ row_end,
        const int* __restrict__ csr_src, const float* __restrict__ dis,
        const unsigned short* __restrict__ gin, const float* __restrict__ bin,
        const float* __restrict__ W, const float* __restrict__ bout,
        void* __restrict__ o_, int M) {
    constexpr int VEC = F / LPN;      // bf16 per lane
    constexpr int NPB = 256 / LPN;
    constexpr int HSS = F + 4;
    __shared__ float Ws[F * FOUT];
    __shared__ float hs[NPB][HSS];
    __shared__ float bs[FINAL ? FOUT : 1];
    const int t = threadIdx.x;
    for (int i = t; i < F * FOUT; i += 256) Ws[i] = W[i];
    if (FINAL && t < FOUT) bs[t] = bout[t];
    const int grp = t / LPN, gl = t % LPN;
    const int n = blockIdx.x * NPB + grp;
    float dn = 0.f;
    if (n < M) {
        const int rs = row_start[n], re = row_end[n];
        dn = dis[n];
        float acc[VEC] = {};
        int i = rs;
        while (i < re) {
            const int take = re - i;  // uniform within the LPN-lane group
            int s = 0; float wl = 0.f;
            if (gl < take) {
                s = csr_src[i + gl];
                if constexpr (EDGEW) wl = dis[s];
            }
            #pragma unroll
            for (int jj = 0; jj < LPN; ++jj) {
                if (jj < take) {
                    int sj = __shfl(s, jj, LPN);
                    float wj;
                    if constexpr (EDGEW) wj = __shfl(wl, jj, LPN) * dn;
                    if constexpr (VEC == 8) {
                        ushort8v r8 = *(const ushort8v*)(gin + (size_t)sj * F + gl * 8);
                        #pragma unroll
                        for (int k = 0; k < 8; ++k) {
                            float v = bf16tof(r8[k]);
                            if constexpr (EDGEW) acc[k] += wj * v; else acc[k] += v;
                        }
                    } else {
                        ushort4v r4 = *(const ushort4v*)(gin + (size_t)sj * F + gl * 4);
                        #pragma unroll
                        for (int k = 0; k < 4; ++k) {
                            float v = bf16tof(r4[k]);
                            if constexpr (EDGEW) acc[k] += wj * v; else acc[k] += v;
                        }
                    }
                }
            }
            i += LPN;
        }
        // self-loop
        const float sw = EDGEW ? dn * dn : 1.f;
        if constexpr (VEC == 8) {
            ushort8v r8 = *(const ushort8v*)(gin + (size_t)n * F + gl * 8);
            #pragma unroll
            for (int k = 0; k < 8; ++k) acc[k] += sw * bf16tof(r8[k]);
        } else {
            ushort4v r4 = *(const ushort4v*)(gin + (size_t)n * F + gl * 4);
            #pragma unroll
            for (int k = 0; k < 4; ++k) acc[k] += sw * bf16tof(r4[k]);
        }
        #pragma unroll
        for (int k = 0; k < VEC; ++k) {
            float pre = EDGEW ? acc[k] : dn * acc[k];
            float r = pre + bin[gl * VEC + k];
            if (RELU) r = fmaxf(r, 0.f);
            hs[grp][gl * VEC + k] = r;
        }
    }
    __syncthreads();
    if (!FINAL) {
        constexpr int OCPT = FOUT / LPN;
        if (n < M) {
            const int oc0 = gl * OCPT;
            float a[OCPT] = {};
            #pragma unroll
            for (int k = 0; k < F; ++k) {
                float hv = hs[grp][k];
                if constexpr (OCPT == 4) {
                    float4 wv = *(const float4*)&Ws[k * FOUT + oc0];
                    a[0] += hv * wv.x; a[1] += hv * wv.y;
                    a[2] += hv * wv.z; a[3] += hv * wv.w;
                } else {
                    float2 wv = *(const float2*)&Ws[k * FOUT + oc0];
                    a[0] += hv * wv.x; a[1] += hv * wv.y;
                }
            }
            unsigned short* o = (unsigned short*)o_;
            if constexpr (OCPT == 4) {
                ushort4v pk;
                #pragma unroll
                for (int j = 0; j < 4; ++j) pk[j] = bf16rne(a[j] * dn);
                *(ushort4v*)(o + (size_t)n * FOUT + oc0) = pk;
            } else {
                #pragma unroll
                for (int j = 0; j < OCPT; ++j)
                    o[(size_t)n * FOUT + oc0 + j] = bf16rne(a[j] * dn);
            }
        }
    } else {
        float* o = (float*)o_;
        for (int idx = t; idx < NPB * FOUT; idx += 256) {
            int nl = idx / FOUT, oc = idx % FOUT;
            int nn = blockIdx.x * NPB + nl;
            if (nn >= M) continue;
            float a = bs[oc];
            #pragma unroll
            for (int k = 0; k < F; ++k) a += hs[nl][k] * Ws[k * FOUT + oc];
            o[(size_t)nn * FOUT + oc] = a;
        }
    }
}

extern "C" void kernel_launch(void* const* d_in, const int* in_sizes, int n_in,
                              void* d_out, int out_size, void* d_ws, size_t ws_size,
                              hipStream_t stream) {
    const float* x  = (const float*)d_in[0];
    const int* eidx = (const int*)d_in[1];
    const float* W1 = (const float*)d_in[2];
    const float* b1 = (const float*)d_in[3];
    const float* W2 = (const float*)d_in[4];
    const float* b2 = (const float*)d_in[5];
    const float* W3 = (const float*)d_in[6];
    const float* b3 = (const float*)d_in[7];
    const float* Wl = (const float*)d_in[8];
    const float* bl = (const float*)d_in[9];
    float* out = (float*)d_out;

    const int M = in_sizes[0] / 512;
    const int E = in_sizes[1] / 2;
    const int* src = eidx;
    const int* dst = eidx + E;
    const int NB = ceil_div_i(M, 512);   // 196 for M=100k
    const int EB = ceil_div_i(E, SCHUNK);
    const int NT = ceil_div_i(M, 64);    // gemm1 tiles

    // workspace (~49 MB)
    char* ws = (char*)d_ws;
    const size_t szM1 = ((size_t)(M + 1) * 4 + 255) & ~(size_t)255;
    const size_t szAR = ((size_t)NB * CAP * 4 + 255) & ~(size_t)255;
    size_t off = 0;
    int*      gtail     = (int*)(ws + off); off += 1024;
    int*      row_start = (int*)(ws + off); off += szM1;
    int*      row_end   = (int*)(ws + off); off += szM1;
    float*    dis       = (float*)(ws + off); off += szM1;
    unsigned* abuf      = (unsigned*)(ws + off); off += szAR;
    int*      csr_src   = (int*)(ws + off); off += szAR;
    unsigned short* wt  = (unsigned short*)(ws + off); off += 66560;
    unsigned short* g1  = (unsigned short*)(ws + off);
    off += ((size_t)M * 64 * 2 + 255) & ~(size_t)255;
    unsigned short* g2  = (unsigned short*)(ws + off);
    off += ((size_t)M * 32 * 2 + 255) & ~(size_t)255;
    unsigned short* g3  = (unsigned short*)(ws + off);
    off += ((size_t)M * 16 * 2 + 255) & ~(size_t)255;

    // D1: init (gtail + W1^T)
    init_kernel<<<128, 256, 0, stream>>>(W1, wt, gtail);
    // D2: scatter || gemm1 (independent)
    scatter_gemm1_kernel<<<EB + NT, 256, 0, stream>>>(src, dst, gtail, abuf, E, EB,
                                                      x, wt, g1, M);
    // D3: build CSR + dis
    build_kernel<<<NB, 256, 0, stream>>>(gtail, abuf, row_start, row_end, dis, csr_src, M);

    // D4: layer 1 (edge-weighted, unscaled g1 in, pre-scaled g2 out)
    gather_mlp_kernel<64, 32, 8, true, false, true><<<ceil_div_i(M, 32), 256, 0, stream>>>(
        row_start, row_end, csr_src, dis, g1, b1, W2, nullptr, g2, M);
    // D5: layer 2 (weight-free)
    gather_mlp_kernel<32, 16, 8, true, false, false><<<ceil_div_i(M, 32), 256, 0, stream>>>(
        row_start, row_end, csr_src, dis, g2, b2, W3, nullptr, g3, M);
    // D6: layer 3 + final linear (weight-free, f32 out)
    gather_mlp_kernel<16, 7, 4, false, true, false><<<ceil_div_i(M, 64), 256, 0, stream>>>(
        row_start, row_end, csr_src, dis, g3, b3, Wl, bl, out, M);
}

// Round 11
// 179.528 us; speedup vs baseline: 14.4410x; 1.1942x over previous
//
#include <hip/hip_runtime.h>

// GCN 3-layer on MI355X. R11: gemm1 rewritten as LDS-staged MFMA GEMM
// (global_load_lds width-16, XOR-swizzled x tile, padded LDS wt tile) —
// R10 unmasked gemm1 at ~117us with sparse-line 16B-stride-2KB fragment
// loads; this makes all global traffic line-dense. Everything else = R10.
// 6 dispatches: init -> [scatter||gemm1] -> build -> g1 -> g2 -> g3.

typedef __bf16 bf16x8 __attribute__((ext_vector_type(8)));
typedef short short8v __attribute__((ext_vector_type(8)));
typedef unsigned short ushort8v __attribute__((ext_vector_type(8)));
typedef unsigned short ushort4v __attribute__((ext_vector_type(4)));
typedef float float4v __attribute__((ext_vector_type(4)));

static inline int ceil_div_i(long long a, long long b) { return (int)((a + b - 1) / b); }

#define CAP 16384      // per-bucket arena capacity
#define SCHUNK 8192    // edges per scatter block
#define RPB 128        // gemm1 rows per block

#define GLOAD_LDS16(gsrc, ldst)                                                  \
    __builtin_amdgcn_global_load_lds(                                            \
        (const __attribute__((address_space(1))) unsigned*)(gsrc),               \
        (__attribute__((address_space(3))) unsigned*)(ldst), 16, 0, 0)

__device__ inline unsigned short bf16rne(float f) {
    union { float f; unsigned u; } c; c.f = f;
    unsigned u = c.u;
    u += 0x7fffu + ((u >> 16) & 1u);
    return (unsigned short)(u >> 16);
}
__device__ inline float bf16tof(unsigned short h) {
    return __uint_as_float((unsigned)h << 16);
}

// ---------------- D1: arena tails + W1 -> bf16 transposed [64][512] ----------------
__global__ __launch_bounds__(256) void init_kernel(const float* __restrict__ W1,
                                                   unsigned short* __restrict__ wt,
                                                   int* __restrict__ gtail) {
    const int t = threadIdx.x;
    if (blockIdx.x == 0) gtail[t] = t * CAP;
    for (int i = blockIdx.x * 256 + t; i < 512 * 64; i += gridDim.x * 256) {
        int k = i >> 6, n = i & 63;
        wt[(size_t)n * 512 + k] = bf16rne(W1[i]);
    }
}

// ---------------- D2: FAT — arena scatter || LDS-staged GEMM1 MFMA ----------------
// blocks [0,EB): scatter edges into per-bucket arena; abuf = (dst&511)<<23|src
// blocks [EB,EB+NT): 128-row tiles of g1 = bf16(x @ W1), canonical LDS-staged.
__global__ __launch_bounds__(256) void scatter_gemm1_kernel(
        const int* __restrict__ src, const int* __restrict__ dst,
        int* __restrict__ gtail, unsigned* __restrict__ abuf, int E, int EB,
        const float* __restrict__ x, const unsigned short* __restrict__ wt,
        unsigned short* __restrict__ g1, int M) {
    __shared__ int cur[256];
    __shared__ __align__(16) char xs[RPB * 32 * 4];           // 16 KB fp32 tile, swizzled
    __shared__ __align__(16) unsigned short wst[64 * 40];     // 5 KB padded wt chunk
    const int t = threadIdx.x;
    if (blockIdx.x < EB) {
        // ---- scatter path ----
        const int e0 = blockIdx.x * SCHUNK;
        const int e1 = min(e0 + SCHUNK, E);
        cur[t] = 0;
        __syncthreads();
        for (int e = e0 + t; e < e1; e += 256) atomicAdd(&cur[dst[e] >> 9], 1);
        __syncthreads();
        int c = cur[t];
        cur[t] = c ? atomicAdd(&gtail[t], c) : 0;
        __syncthreads();
        for (int e = e0 + t; e < e1; e += 256) {
            int d = dst[e];
            int pos = atomicAdd(&cur[d >> 9], 1);
            abuf[pos] = ((unsigned)(d & 511) << 23) | (unsigned)src[e];
        }
        return;
    }
    // ---- gemm1 path ----
    const int tile = blockIdx.x - EB;
    const int w = t >> 6, l = t & 63;
    const int lr = l & 15, g = l >> 4;
    const int row0 = tile * RPB;
    float4v acc[2][4] = {};  // [row-subtile st][col-tile f]

    for (int c = 0; c < 16; ++c) {     // K chunks of 32
        const int k0 = c * 32;
        if (c) __syncthreads();        // prev chunk's LDS reads drained
        // stage x tile [128][32] f32 -> LDS, swizzled (byte ^= (row&7)<<4).
        // linear dest, pre-swizzled per-lane global source (both-sides rule).
        {
            char* ldsb = xs + w * 4096;  // wave-uniform base
            #pragma unroll
            for (int j = 0; j < 4; ++j) {
                int o = w * 4096 + j * 1024 + l * 16;
                int r = o >> 7;                        // tile row 0..127
                int colb = (o & 127) ^ ((r & 7) << 4);
                int grow = row0 + r;
                if (grow >= M) grow = 0;               // clamp (rows discarded)
                const char* gs = (const char*)x + (size_t)grow * 2048 +
                                 (size_t)k0 * 4 + colb;
                GLOAD_LDS16(gs, ldsb + j * 1024);
            }
        }
        // stage wt chunk [64 cols][32 k] bf16 -> padded LDS [64][40]
        {
            int n = t >> 2, q = t & 3;
            ushort8v v = *(const ushort8v*)(wt + (size_t)n * 512 + k0 + q * 8);
            *(ushort8v*)&wst[n * 40 + q * 8] = v;
        }
        __syncthreads();
        // B fragments (col n = f*16+lr, k = g*8..+8)
        bf16x8 bf[4];
        #pragma unroll
        for (int f = 0; f < 4; ++f)
            bf[f] = *(const bf16x8*)&wst[(f * 16 + lr) * 40 + g * 8];
        // A fragments + MFMA per row-subtile
        #pragma unroll
        for (int st = 0; st < 2; ++st) {
            const int r = w * 32 + st * 16 + lr;
            const int swz = (r & 7) << 4;
            const char* base = xs + r * 128;
            float4 xa = *(const float4*)(base + ((g * 32) ^ swz));
            float4 xb = *(const float4*)(base + ((g * 32 + 16) ^ swz));
            short8v av;
            av[0] = (short)bf16rne(xa.x); av[1] = (short)bf16rne(xa.y);
            av[2] = (short)bf16rne(xa.z); av[3] = (short)bf16rne(xa.w);
            av[4] = (short)bf16rne(xb.x); av[5] = (short)bf16rne(xb.y);
            av[6] = (short)bf16rne(xb.z); av[7] = (short)bf16rne(xb.w);
            bf16x8 a = __builtin_bit_cast(bf16x8, av);
            #pragma unroll
            for (int f = 0; f < 4; ++f)
                acc[st][f] = __builtin_amdgcn_mfma_f32_16x16x32_bf16(a, bf[f],
                                                                     acc[st][f], 0, 0, 0);
        }
    }
    // C write: row = row0 + w*32 + st*16 + 4g + r, col = f*16 + lr
    #pragma unroll
    for (int st = 0; st < 2; ++st) {
        const int ro0 = row0 + w * 32 + st * 16 + 4 * g;
        #pragma unroll
        for (int r = 0; r < 4; ++r) {
            int ro = ro0 + r;
            if (ro < M) {
                #pragma unroll
                for (int f = 0; f < 4; ++f)
                    g1[(size_t)ro * 64 + f * 16 + lr] = bf16rne(acc[st][f][r]);
            }
        }
    }
}

// ---------------- D3: per-bucket hist+scan -> row_start/row_end/dis, place csr ----------------
__global__ __launch_bounds__(256) void build_kernel(const int* __restrict__ gtail,
                                                    const unsigned* __restrict__ abuf,
                                                    int* __restrict__ row_start,
                                                    int* __restrict__ row_end,
                                                    float* __restrict__ dis,
                                                    int* __restrict__ csr_src, int M) {
    __shared__ int hist[512];
    __shared__ int cur[512];
    __shared__ int wsum_[4];
    const int b = blockIdx.x, t = threadIdx.x, lane = t & 63, wid = t >> 6;
    const int n0 = b << 9;
    const int s = b * CAP;
    const int e = gtail[b];
    hist[t] = 0; hist[t + 256] = 0;
    __syncthreads();
    for (int i = s + t; i < e; i += 256) atomicAdd(&hist[abuf[i] >> 23], 1);
    __syncthreads();
    int c0 = hist[2 * t], c1 = hist[2 * t + 1];
    int pair = c0 + c1;
    int inc = pair;
    #pragma unroll
    for (int d = 1; d < 64; d <<= 1) {
        int o = __shfl_up(inc, d);
        if (lane >= d) inc += o;
    }
    if (lane == 63) wsum_[wid] = inc;
    __syncthreads();
    int wpre = 0;
    for (int ww = 0; ww < wid; ++ww) wpre += wsum_[ww];
    int excl = wpre + inc - pair;
    int r0 = s + excl, r1 = r0 + c0;
    int n = n0 + 2 * t;
    if (n < M) {
        row_start[n] = r0; row_end[n] = r1;
        dis[n] = rsqrtf((float)(c0 + 1));
    }
    if (n + 1 < M) {
        row_start[n + 1] = r1; row_end[n + 1] = r1 + c1;
        dis[n + 1] = rsqrtf((float)(c1 + 1));
    }
    cur[2 * t] = r0; cur[2 * t + 1] = r1;
    __syncthreads();
    for (int i = s + t; i < e; i += 256) {
        unsigned p = abuf[i];
        int pos = atomicAdd(&cur[p >> 23], 1);
        csr_src[pos] = (int)(p & 0x7fffffu);
    }
}

// ---------------- D4-D6: gather + fused MLP ----------------
// EDGEW (layer1): acc = sum_e dis[s]*dn*gin[s] + dn^2*gin[n]; h = act(acc+bin)
// else (pre-scaled gin): acc = sum_e gin[s] + gin[n];        h = act(dn*acc+bin)
// non-final: o[n] = bf16(dn * (h @ W));  final: o[n] = h @ Wl + bl (f32)
template <int F, int FOUT, int LPN, bool RELU, bool FINAL, bool EDGEW>
__global__ __launch_bounds__(256) void gather_mlp_kernel(
        const int* __restrict__ row_start, const int* __restrict__ row_end,
        const int* __restrict__ csr_src, const float* __restrict__ dis,
        const unsigned short* __restrict__ gin, const float* __restrict__ bin,
        const float* __restrict__ W, const float* __restrict__ bout,
        void* __restrict__ o_, int M) {
    constexpr int VEC = F / LPN;
    constexpr int NPB = 256 / LPN;
    constexpr int HSS = F + 4;
    __shared__ float Ws[F * FOUT];
    __shared__ float hs[NPB][HSS];
    __shared__ float bs[FINAL ? FOUT : 1];
    const int t = threadIdx.x;
    for (int i = t; i < F * FOUT; i += 256) Ws[i] = W[i];
    if (FINAL && t < FOUT) bs[t] = bout[t];
    const int grp = t / LPN, gl = t % LPN;
    const int n = blockIdx.x * NPB + grp;
    float dn = 0.f;
    if (n < M) {
        const int rs = row_start[n], re = row_end[n];
        dn = dis[n];
        float acc[VEC] = {};
        int i = rs;
        while (i < re) {
            const int take = re - i;
            int s = 0; float wl = 0.f;
            if (gl < take) {
                s = csr_src[i + gl];
                if constexpr (EDGEW) wl = dis[s];
            }
            #pragma unroll
            for (int jj = 0; jj < LPN; ++jj) {
                if (jj < take) {
                    int sj = __shfl(s, jj, LPN);
                    float wj;
                    if constexpr (EDGEW) wj = __shfl(wl, jj, LPN) * dn;
                    if constexpr (VEC == 8) {
                        ushort8v r8 = *(const ushort8v*)(gin + (size_t)sj * F + gl * 8);
                        #pragma unroll
                        for (int k = 0; k < 8; ++k) {
                            float v = bf16tof(r8[k]);
                            if constexpr (EDGEW) acc[k] += wj * v; else acc[k] += v;
                        }
                    } else {
                        ushort4v r4 = *(const ushort4v*)(gin + (size_t)sj * F + gl * 4);
                        #pragma unroll
                        for (int k = 0; k < 4; ++k) {
                            float v = bf16tof(r4[k]);
                            if constexpr (EDGEW) acc[k] += wj * v; else acc[k] += v;
                        }
                    }
                }
            }
            i += LPN;
        }
        const float sw = EDGEW ? dn * dn : 1.f;
        if constexpr (VEC == 8) {
            ushort8v r8 = *(const ushort8v*)(gin + (size_t)n * F + gl * 8);
            #pragma unroll
            for (int k = 0; k < 8; ++k) acc[k] += sw * bf16tof(r8[k]);
        } else {
            ushort4v r4 = *(const ushort4v*)(gin + (size_t)n * F + gl * 4);
            #pragma unroll
            for (int k = 0; k < 4; ++k) acc[k] += sw * bf16tof(r4[k]);
        }
        #pragma unroll
        for (int k = 0; k < VEC; ++k) {
            float pre = EDGEW ? acc[k] : dn * acc[k];
            float r = pre + bin[gl * VEC + k];
            if (RELU) r = fmaxf(r, 0.f);
            hs[grp][gl * VEC + k] = r;
        }
    }
    __syncthreads();
    if (!FINAL) {
        constexpr int OCPT = FOUT / LPN;
        if (n < M) {
            const int oc0 = gl * OCPT;
            float a[OCPT] = {};
            #pragma unroll
            for (int k = 0; k < F; ++k) {
                float hv = hs[grp][k];
                if constexpr (OCPT == 4) {
                    float4 wv = *(const float4*)&Ws[k * FOUT + oc0];
                    a[0] += hv * wv.x; a[1] += hv * wv.y;
                    a[2] += hv * wv.z; a[3] += hv * wv.w;
                } else {
                    float2 wv = *(const float2*)&Ws[k * FOUT + oc0];
                    a[0] += hv * wv.x; a[1] += hv * wv.y;
                }
            }
            unsigned short* o = (unsigned short*)o_;
            if constexpr (OCPT == 4) {
                ushort4v pk;
                #pragma unroll
                for (int j = 0; j < 4; ++j) pk[j] = bf16rne(a[j] * dn);
                *(ushort4v*)(o + (size_t)n * FOUT + oc0) = pk;
            } else {
                #pragma unroll
                for (int j = 0; j < OCPT; ++j)
                    o[(size_t)n * FOUT + oc0 + j] = bf16rne(a[j] * dn);
            }
        }
    } else {
        float* o = (float*)o_;
        for (int idx = t; idx < NPB * FOUT; idx += 256) {
            int nl = idx / FOUT, oc = idx % FOUT;
            int nn = blockIdx.x * NPB + nl;
            if (nn >= M) continue;
            float a = bs[oc];
            #pragma unroll
            for (int k = 0; k < F; ++k) a += hs[nl][k] * Ws[k * FOUT + oc];
            o[(size_t)nn * FOUT + oc] = a;
        }
    }
}

extern "C" void kernel_launch(void* const* d_in, const int* in_sizes, int n_in,
                              void* d_out, int out_size, void* d_ws, size_t ws_size,
                              hipStream_t stream) {
    const float* x  = (const float*)d_in[0];
    const int* eidx = (const int*)d_in[1];
    const float* W1 = (const float*)d_in[2];
    const float* b1 = (const float*)d_in[3];
    const float* W2 = (const float*)d_in[4];
    const float* b2 = (const float*)d_in[5];
    const float* W3 = (const float*)d_in[6];
    const float* b3 = (const float*)d_in[7];
    const float* Wl = (const float*)d_in[8];
    const float* bl = (const float*)d_in[9];
    float* out = (float*)d_out;

    const int M = in_sizes[0] / 512;
    const int E = in_sizes[1] / 2;
    const int* src = eidx;
    const int* dst = eidx + E;
    const int NB = ceil_div_i(M, 512);
    const int EB = ceil_div_i(E, SCHUNK);
    const int NT = ceil_div_i(M, RPB);   // gemm1 tiles (128 rows)

    // workspace (~49 MB)
    char* ws = (char*)d_ws;
    const size_t szM1 = ((size_t)(M + 1) * 4 + 255) & ~(size_t)255;
    const size_t szAR = ((size_t)NB * CAP * 4 + 255) & ~(size_t)255;
    size_t off = 0;
    int*      gtail     = (int*)(ws + off); off += 1024;
    int*      row_start = (int*)(ws + off); off += szM1;
    int*      row_end   = (int*)(ws + off); off += szM1;
    float*    dis       = (float*)(ws + off); off += szM1;
    unsigned* abuf      = (unsigned*)(ws + off); off += szAR;
    int*      csr_src   = (int*)(ws + off); off += szAR;
    unsigned short* wt  = (unsigned short*)(ws + off); off += 66560;
    unsigned short* g1  = (unsigned short*)(ws + off);
    off += ((size_t)M * 64 * 2 + 255) & ~(size_t)255;
    unsigned short* g2  = (unsigned short*)(ws + off);
    off += ((size_t)M * 32 * 2 + 255) & ~(size_t)255;
    unsigned short* g3  = (unsigned short*)(ws + off);
    off += ((size_t)M * 16 * 2 + 255) & ~(size_t)255;

    // D1: init (gtail + W1^T)
    init_kernel<<<128, 256, 0, stream>>>(W1, wt, gtail);
    // D2: scatter || gemm1 (independent)
    scatter_gemm1_kernel<<<EB + NT, 256, 0, stream>>>(src, dst, gtail, abuf, E, EB,
                                                      x, wt, g1, M);
    // D3: build CSR + dis
    build_kernel<<<NB, 256, 0, stream>>>(gtail, abuf, row_start, row_end, dis, csr_src, M);

    // D4: layer 1 (edge-weighted, unscaled g1 in, pre-scaled g2 out)
    gather_mlp_kernel<64, 32, 8, true, false, true><<<ceil_div_i(M, 32), 256, 0, stream>>>(
        row_start, row_end, csr_src, dis, g1, b1, W2, nullptr, g2, M);
    // D5: layer 2 (weight-free)
    gather_mlp_kernel<32, 16, 8, true, false, false><<<ceil_div_i(M, 32), 256, 0, stream>>>(
        row_start, row_end, csr_src, dis, g2, b2, W3, nullptr, g3, M);
    // D6: layer 3 + final linear (weight-free, f32 out)
    gather_mlp_kernel<16, 7, 4, false, true, false><<<ceil_div_i(M, 64), 256, 0, stream>>>(
        row_start, row_end, csr_src, dis, g3, b3, Wl, bl, out, M);
}